// Round 4
// baseline (1239.872 us; speedup 1.0000x reference)
//
#include <hip/hip_runtime.h>
#include <hip/hip_bf16.h>
#include <stdint.h>

// Problem constants (S=8, B=16, N=500, D=128, K=50, L=6)
#define G_      128
#define N_      500
#define NP_     512          // padded N (stride)
#define D_      128
#define K_      50
#define L_      6
#define NW_     16           // adjacency words per row
#define ROWT    125
#define STRIDE_ 160          // max symmetric degree capacity

typedef __attribute__((ext_vector_type(8))) short bf16x8;
typedef __attribute__((ext_vector_type(4))) float f32x4;

#define ADJ_BYTES  ((size_t)G_ * N_ * NW_ * 4)      //  4,096,000
#define EJ_BYTES   ((size_t)G_ * N_ * STRIDE_ * 2)  // 20,480,000
#define ED_BYTES   ((size_t)G_ * N_ * STRIDE_ * 4)  // 40,960,000
#define DO_BYTES   ((size_t)G_ * N_ * 8)            //    512,000
#define HB_BYTES   ((size_t)G_ * NP_ * D_ * 2)      // 16,777,216 each
#define WT_BYTES   ((size_t)L_ * D_ * D_ * 2)       //    196,608

__device__ __forceinline__ float silu_f(float z) {
    return z * __builtin_amdgcn_rcpf(1.0f + __expf(-z));
}
__device__ __forceinline__ unsigned short f2bf(float f) {
    uint32_t u = __float_as_uint(f);
    u += 0x7fffu + ((u >> 16) & 1u);
    return (unsigned short)(u >> 16);
}
__device__ __forceinline__ float bf2f(unsigned short s) {
    return __uint_as_float(((uint32_t)s) << 16);
}
__device__ __forceinline__ void gload16(const void* src, void* dst) {
    __builtin_amdgcn_global_load_lds(
        (__attribute__((address_space(1))) void*)(void*)(uintptr_t)src,
        (__attribute__((address_space(3))) void*)dst, 16, 0, 0);
}

// ---------------------------------------------------------------------------
// K0: kNN via exact bitwise binary-search of the 50th smallest distance.
// Real distances are in [1e-6, 2) -> float bits 30..28 fixed at 0,1,1:
// start prefix at 0x30000000 and search 28 bits. One wave per row.
// ---------------------------------------------------------------------------
__global__ __launch_bounds__(256) void knn_kernel(const float* __restrict__ x,
                                                  uint32_t* __restrict__ adj) {
    int g    = blockIdx.x / ROWT;
    int tile = blockIdx.x % ROWT;
    int wv   = threadIdx.x >> 6;
    int lane = threadIdx.x & 63;
    int i    = tile * 4 + wv;

    __shared__ float2 c[N_];
    for (int t = threadIdx.x; t < N_; t += 256)
        c[t] = ((const float2*)x)[(size_t)g * N_ + t];
    __syncthreads();

    float2 ci = c[i];
    uint32_t kb[8];
#pragma unroll
    for (int r = 0; r < 8; ++r) {
        int j = lane + r * 64;
        float dv;
        if (j < N_ && j != i) {
            float dx = ci.x - c[j].x, dy = ci.y - c[j].y;
            dv = sqrtf(dx * dx + dy * dy + 1e-12f);
        } else {
            dv = 3.0e38f;
        }
        kb[r] = __float_as_uint(dv);
    }

    uint32_t prefix = 0x30000000u;
    for (int bit = 27; bit >= 0; --bit) {
        uint32_t cand = prefix | (1u << bit);
        int cnt = 0;
#pragma unroll
        for (int r = 0; r < 8; ++r)
            cnt += __popcll(__ballot(kb[r] < cand));
        if (cnt < K_) prefix = cand;
    }

    unsigned long long sel[8];
    int cntless = 0;
#pragma unroll
    for (int r = 0; r < 8; ++r) {
        sel[r] = __ballot(kb[r] < prefix);
        cntless += __popcll(sel[r]);
    }
    int rem = K_ - cntless;
    unsigned long long tb[8];
    int tietot = 0;
#pragma unroll
    for (int r = 0; r < 8; ++r) {
        tb[r] = __ballot(kb[r] == prefix);
        tietot += __popcll(tb[r]);
    }
    if (tietot == rem) {
#pragma unroll
        for (int r = 0; r < 8; ++r) sel[r] |= tb[r];
    } else {
#pragma unroll
        for (int r = 0; r < 8; ++r) {
            unsigned long long t2 = tb[r];
            while (rem > 0 && t2) {
                unsigned long long lb = t2 & (~t2 + 1ull);
                sel[r] |= lb;
                t2 ^= lb;
                --rem;
            }
        }
    }

    uint32_t* arow = adj + ((size_t)g * N_ + i) * NW_;
#pragma unroll
    for (int r = 0; r < 8; ++r) {
        if (lane == 2 * r)     arow[2 * r]     = (uint32_t)sel[r];
        if (lane == 2 * r + 1) arow[2 * r + 1] = (uint32_t)(sel[r] >> 32);
    }
}

// ---------------------------------------------------------------------------
// K0b: symmetrize bitmask in LDS, emit per-row j-sorted (j, dist) edge lists
// plus packed per-64-tile cumulative offsets (u8 x 8 in a u64).
// One block per graph.
// ---------------------------------------------------------------------------
__global__ __launch_bounds__(512) void eprep_kernel(const float* __restrict__ x,
                                                    const uint32_t* __restrict__ adj,
                                                    uint16_t* __restrict__ ej,
                                                    float* __restrict__ ed,
                                                    unsigned long long* __restrict__ degoff) {
    int g = blockIdx.x, tid = threadIdx.x;
    __shared__ uint32_t am[N_][NW_];   // 32,000 B
    __shared__ float2   c[N_];         //  4,000 B

    for (int t = tid; t < N_; t += 512)
        c[t] = ((const float2*)x)[(size_t)g * N_ + t];
    const uint32_t* ag = adj + (size_t)g * N_ * NW_;
    for (int t = tid; t < N_ * NW_; t += 512)
        ((uint32_t*)am)[t] = ag[t];
    __syncthreads();

    uint32_t buf[16];
    int cnt = 0;
    for (int idx = tid; idx < N_ * NW_; idx += 512) {
        int ii = idx >> 4, w = idx & 15;
        uint32_t v = am[ii][w];
        int jb = w << 5;
        int jmax = (jb + 32 <= N_) ? 32 : (N_ - jb);
        uint32_t wi = (uint32_t)ii >> 5, bi = ii & 31;
        for (int b = 0; b < jmax; ++b)
            v |= ((am[jb + b][wi] >> bi) & 1u) << b;
        buf[cnt++] = v;
    }
    __syncthreads();
    cnt = 0;
    for (int idx = tid; idx < N_ * NW_; idx += 512)
        am[idx >> 4][idx & 15] = buf[cnt++];
    __syncthreads();

    int wv = tid >> 6, lane = tid & 63;
    for (int i = wv; i < N_; i += 8) {
        uint32_t w = (lane < NW_) ? am[i][lane] : 0u;
        int pc = __popc(w);
        int pref = pc;
#pragma unroll
        for (int off = 1; off < 16; off <<= 1) {
            int o = __shfl_up(pref, off);
            if (lane >= off) pref += o;
        }
        unsigned long long pk = 0;
#pragma unroll
        for (int t = 0; t < 8; ++t) {
            int cum = __shfl(pref, 2 * t + 1);   // inclusive count through tile t
            if (cum > STRIDE_) cum = STRIDE_;
            pk |= (unsigned long long)(cum & 0xff) << (8 * t);
        }
        if (lane == 0) degoff[(size_t)g * N_ + i] = pk;
        int base = pref - pc;
        float2 ci = c[i];
        size_t eoff = ((size_t)g * N_ + i) * STRIDE_;
        uint32_t ww = w;
        int slot = base;
        while (ww) {
            int b = __ffs(ww) - 1;
            ww &= ww - 1;
            int j = (lane << 5) + b;
            float dx = ci.x - c[j].x, dy = ci.y - c[j].y;
            float dd = sqrtf(dx * dx + dy * dy + 1e-12f);
            if (slot < STRIDE_) {
                ej[eoff + slot] = (uint16_t)j;
                ed[eoff + slot] = dd;
            }
            ++slot;
        }
    }
}

// ---------------------------------------------------------------------------
// K0c: transpose weights to bf16: WT[l][dout][din] = bf16(W[l][din][dout])
// ---------------------------------------------------------------------------
__global__ __launch_bounds__(256) void wprep_kernel(const float* __restrict__ Ws,
                                                    const float* __restrict__ Wm,
                                                    unsigned short* __restrict__ WsT,
                                                    unsigned short* __restrict__ WmT) {
    int idx = blockIdx.x * 256 + threadIdx.x;
    int half = idx >= L_ * D_ * D_;
    int r = half ? idx - L_ * D_ * D_ : idx;
    int l = r >> 14, rr = r & 16383, dout = rr >> 7, din = rr & 127;
    const float* W = half ? Wm : Ws;
    unsigned short* O = half ? WmT : WsT;
    O[r] = f2bf(W[(size_t)l * 16384 + din * 128 + dout]);
}

// ---------------------------------------------------------------------------
// K1: h0 = silu(coords @ Wn + bn), written bf16 as h[i][d] AND hT[d][i]
// ---------------------------------------------------------------------------
__global__ __launch_bounds__(256) void enc_kernel(const float* __restrict__ x,
                                                  const float* __restrict__ Wn,
                                                  const float* __restrict__ bn,
                                                  unsigned short* __restrict__ h,
                                                  unsigned short* __restrict__ hT) {
    int g = blockIdx.x, tid = threadIdx.x;
    __shared__ float2 c[N_];
    for (int t = tid; t < N_; t += 256)
        c[t] = ((const float2*)x)[(size_t)g * N_ + t];
    __syncthreads();
    for (int o = tid; o < N_ * 16; o += 256) {
        int i = o >> 4, d0 = (o & 15) * 8;
        float2 ci = c[i];
        unsigned short u[8];
#pragma unroll
        for (int e = 0; e < 8; ++e) {
            int d = d0 + e;
            u[e] = f2bf(silu_f(ci.x * Wn[d] + ci.y * Wn[D_ + d] + bn[d]));
        }
        *(uint4*)&h[((size_t)g * NP_ + i) * D_ + d0] = *(uint4*)u;
    }
    for (int o = tid; o < D_ * 64; o += 256) {
        int d = o >> 6, io = o & 63;
        float w0 = Wn[d], w1 = Wn[D_ + d], b = bn[d];
        unsigned short u[8];
#pragma unroll
        for (int e = 0; e < 8; ++e) {
            int i = io * 8 + e;
            unsigned short val = 0;
            if (i < N_) {
                float2 ci = c[i];
                val = f2bf(silu_f(ci.x * w0 + ci.y * w1 + b));
            }
            u[e] = val;
        }
        *(uint4*)&hT[((size_t)g * D_ + d) * NP_ + io * 8] = *(uint4*)u;
    }
}

// ---------------------------------------------------------------------------
// K2: fused layer. Phase 1: mT = hT @ gateT via MFMA, gate tile built by
// zero-fill + sparse scatter of silu(we*dist+be) from precomputed edge lists,
// double-buffered with global_load_lds staging of hT (1 barrier/j-tile).
// Phase 2: h_new^T = [WsT|WmT] @ [h|m]^T (128x128, K=256) MFMA + bias + silu.
// Grid: G*4. 8 waves = 2(dout) x 4(i). 128KB dynamic LDS.
// ---------------------------------------------------------------------------
__global__ __launch_bounds__(512, 1) void layer_kernel(
    const uint16_t* __restrict__ ej,
    const float* __restrict__ ed,
    const unsigned long long* __restrict__ degoff,
    const unsigned short* __restrict__ hin,    // [G][NP_][D_]
    const unsigned short* __restrict__ hinT,   // [G][D_][NP_]
    unsigned short* __restrict__ hout,
    unsigned short* __restrict__ houtT,
    const unsigned short* __restrict__ WsT,    // [L][dout][din] bf16
    const unsigned short* __restrict__ WmT,
    const float* __restrict__ bL,
    const float* __restrict__ we,
    const float* __restrict__ be, int l)
{
    int g  = blockIdx.x >> 2;
    int it = blockIdx.x & 3;
    int i0 = it * 128;
    int tid = threadIdx.x;
    int lane = tid & 63, wv = tid >> 6;
    int wrow = wv >> 2, wcol = wv & 3;

    extern __shared__ char lds[];
    char* hTA0 = lds;                // [128 d][64 j] bf16 swizzled, 16 KB
    char* hTA1 = lds + 16384;
    char* gt0  = lds + 32768;        // [128 i][64 j] bf16 swizzled, 16 KB
    char* gt1  = lds + 49152;
    char* Astk = lds;                // phase 2: [128 dout][256 k] bf16, 64 KB
    char* Bh   = lds + 65536;        // phase 2: [128 i][128 k] bf16, 32 KB
    char* Bm   = lds + 98304;        // phase 2: [128 i][128 k] bf16, 32 KB

    float wel = we[l], bel = be[l];
    const unsigned short* hTg = hinT + (size_t)g * D_ * NP_;

    // ---- phase-1 staging helpers ----
    auto stage_hT = [&](char* buf, int jt) {
        int j0 = jt * 64;
#pragma unroll
        for (int p = 0; p < 2; ++p) {
            int o = tid + p * 512;
            int d = o >> 3, joL = o & 7;
            int jo = joL ^ (d & 7);                     // source pre-swizzle
            gload16(hTg + (size_t)d * NP_ + j0 + jo * 8, buf + o * 16);
        }
    };
    auto build_gate = [&](char* buf, int jt) {
        // zero this wave's own rows (il mod 8 == wv)
        const uint4 z4 = make_uint4(0u, 0u, 0u, 0u);
#pragma unroll
        for (int z = 0; z < 2; ++z) {
            int s = lane + z * 64;                      // 0..127
            int rr = s >> 3, q = s & 7;
            int il = wv + rr * 8;
            *(uint4*)(buf + (il << 7) + (q << 4)) = z4;
        }
        asm volatile("s_waitcnt lgkmcnt(0)" ::: "memory");
        int j0 = jt * 64;
        for (int rr = 0; rr < 16; ++rr) {
            int il = wv + rr * 8;
            int gi = i0 + il;
            if (gi >= N_) continue;                     // wave-uniform
            unsigned long long offs = degoff[(size_t)g * N_ + gi];
            int start = jt ? (int)((offs >> (8 * (jt - 1))) & 0xff) : 0;
            int end   = (int)((offs >> (8 * jt)) & 0xff);
            size_t eoff = ((size_t)g * N_ + gi) * STRIDE_;
            for (int e = start + lane; e < end; e += 64) {
                int j   = ej[eoff + e];
                float d = ed[eoff + e];
                float z = wel * d + bel;
                float gv = z * __builtin_amdgcn_rcpf(1.0f + __expf(-z));
                int byt = (il << 7) + ((j - j0) << 1);
                byt ^= (il & 7) << 4;
                *(unsigned short*)(buf + byt) = f2bf(gv);
            }
        }
    };

    f32x4 acc[4][2];
#pragma unroll
    for (int a_ = 0; a_ < 4; ++a_)
#pragma unroll
        for (int b_ = 0; b_ < 2; ++b_)
            acc[a_][b_] = (f32x4){0.f, 0.f, 0.f, 0.f};

    // ---- phase 1: double-buffered j-tiles ----
    stage_hT(hTA0, 0);
    build_gate(gt0, 0);
    __syncthreads();

    for (int jt = 0; jt < 8; ++jt) {
        char* hcur = (jt & 1) ? hTA1 : hTA0;
        char* gcur = (jt & 1) ? gt1  : gt0;
        if (jt < 7) {
            char* hnxt = (jt & 1) ? hTA0 : hTA1;
            char* gnxt = (jt & 1) ? gt0  : gt1;
            stage_hT(hnxt, jt + 1);
            build_gate(gnxt, jt + 1);
        }
#pragma unroll
        for (int kk = 0; kk < 64; kk += 32) {
            int kbyte = (kk + ((lane >> 4) << 3)) << 1;
            bf16x8 af[4], bfr[2];
#pragma unroll
            for (int fr = 0; fr < 4; ++fr) {
                int d = wrow * 64 + fr * 16 + (lane & 15);
                int byt = (d << 7) + kbyte; byt ^= (d & 7) << 4;
                af[fr] = *(const bf16x8*)(hcur + byt);
            }
#pragma unroll
            for (int fc = 0; fc < 2; ++fc) {
                int i = wcol * 32 + fc * 16 + (lane & 15);
                int byt = (i << 7) + kbyte; byt ^= (i & 7) << 4;
                bfr[fc] = *(const bf16x8*)(gcur + byt);
            }
#pragma unroll
            for (int fr = 0; fr < 4; ++fr)
#pragma unroll
                for (int fc = 0; fc < 2; ++fc)
                    acc[fr][fc] = __builtin_amdgcn_mfma_f32_16x16x32_bf16(
                        af[fr], bfr[fc], acc[fr][fc], 0, 0, 0);
        }
        __syncthreads();
    }

    // ---- stage phase 2: Astk + Bh via global_load_lds, m frags -> Bm ----
    const unsigned short* wsp = WsT + (size_t)l * D_ * D_;
    const unsigned short* wmp = WmT + (size_t)l * D_ * D_;
#pragma unroll
    for (int p = 0; p < 8; ++p) {
        int o = tid + p * 512;
        int dout = o >> 5, koL = o & 31;
        int k = koL ^ (dout & 7);                      // source pre-swizzle
        const unsigned short* src = (k < 16) ? (wsp + dout * 128 + k * 8)
                                             : (wmp + dout * 128 + (k - 16) * 8);
        gload16(src, Astk + o * 16);
    }
    const unsigned short* hg = hin + (size_t)g * NP_ * D_;
#pragma unroll
    for (int p = 0; p < 4; ++p) {
        int o = tid + p * 512;
        int il = o >> 4, koL = o & 15;
        int k = koL ^ (il & 7);
        gload16(hg + (size_t)(i0 + il) * D_ + k * 8, Bh + o * 16);
    }
#pragma unroll
    for (int fr = 0; fr < 4; ++fr)
#pragma unroll
        for (int fc = 0; fc < 2; ++fc) {
            int dbase = wrow * 64 + fr * 16 + ((lane >> 4) << 2);
            int ib    = wcol * 32 + fc * 16 + (lane & 15);
            f32x4 v = acc[fr][fc];
            uint32_t p0 = (uint32_t)f2bf(v[0]) | ((uint32_t)f2bf(v[1]) << 16);
            uint32_t p1 = (uint32_t)f2bf(v[2]) | ((uint32_t)f2bf(v[3]) << 16);
            int byt = (ib << 8) + (dbase << 1); byt ^= (ib & 7) << 4;
            *(uint32_t*)(Bm + byt)     = p0;
            *(uint32_t*)(Bm + byt + 4) = p1;
        }
    __syncthreads();

    // ---- phase 2: h_new^T = Astk @ B^T  (128x128, K=256) ----
    f32x4 acc2[4][2];
#pragma unroll
    for (int a_ = 0; a_ < 4; ++a_)
#pragma unroll
        for (int b_ = 0; b_ < 2; ++b_)
            acc2[a_][b_] = (f32x4){0.f, 0.f, 0.f, 0.f};

#pragma unroll
    for (int kk = 0; kk < 256; kk += 32) {
        int kks = kk + ((lane >> 4) << 3);
        const char* bbase = (kk < 128) ? Bh : Bm;
        int kbyB = (kk < 128) ? (kks << 1) : ((kks - 128) << 1);
        int kbyA = kks << 1;
        bf16x8 af[4], bfr[2];
#pragma unroll
        for (int fr = 0; fr < 4; ++fr) {
            int d = wrow * 64 + fr * 16 + (lane & 15);
            int byt = (d << 9) + kbyA; byt ^= (d & 7) << 4;
            af[fr] = *(const bf16x8*)(Astk + byt);
        }
#pragma unroll
        for (int fc = 0; fc < 2; ++fc) {
            int i = wcol * 32 + fc * 16 + (lane & 15);
            int byt = (i << 8) + kbyB; byt ^= (i & 7) << 4;
            bfr[fc] = *(const bf16x8*)(bbase + byt);
        }
#pragma unroll
        for (int fr = 0; fr < 4; ++fr)
#pragma unroll
            for (int fc = 0; fc < 2; ++fc)
                acc2[fr][fc] = __builtin_amdgcn_mfma_f32_16x16x32_bf16(
                    af[fr], bfr[fc], acc2[fr][fc], 0, 0, 0);
    }

    // ---- epilogue: bias + silu, write hout[i][d] and houtT[d][i] ----
    const float* blp = bL + (size_t)l * D_;
#pragma unroll
    for (int fr = 0; fr < 4; ++fr)
#pragma unroll
        for (int fc = 0; fc < 2; ++fc) {
            int dbase = wrow * 64 + fr * 16 + ((lane >> 4) << 2);
            int gi = i0 + wcol * 32 + fc * 16 + (lane & 15);
            f32x4 v = acc2[fr][fc];
            float4 bias = *(const float4*)&blp[dbase];
            float o0 = silu_f(v[0] + bias.x);
            float o1 = silu_f(v[1] + bias.y);
            float o2 = silu_f(v[2] + bias.z);
            float o3 = silu_f(v[3] + bias.w);
            size_t tbase = ((size_t)g * D_ + dbase) * NP_ + gi;
            if (gi < N_) {
                uint32_t q0 = (uint32_t)f2bf(o0) | ((uint32_t)f2bf(o1) << 16);
                uint32_t q1 = (uint32_t)f2bf(o2) | ((uint32_t)f2bf(o3) << 16);
                *(uint2*)&hout[((size_t)g * NP_ + gi) * D_ + dbase] = make_uint2(q0, q1);
                houtT[tbase]           = f2bf(o0);
                houtT[tbase + NP_]     = f2bf(o1);
                houtT[tbase + 2 * NP_] = f2bf(o2);
                houtT[tbase + 3 * NP_] = f2bf(o3);
            } else {
                houtT[tbase]           = 0;
                houtT[tbase + NP_]     = 0;
                houtT[tbase + 2 * NP_] = 0;
                houtT[tbase + 3 * NP_] = 0;
            }
        }
}

// ---------------------------------------------------------------------------
// K4: global mean pool + output projection
// ---------------------------------------------------------------------------
__global__ __launch_bounds__(256) void pool_kernel(const unsigned short* __restrict__ h,
                                                   const float* __restrict__ Wo,
                                                   float* __restrict__ out) {
    int g = blockIdx.x, tid = threadIdx.x;
    const unsigned short* hg = h + (size_t)g * NP_ * D_;
    float a8[8];
#pragma unroll
    for (int e = 0; e < 8; ++e) a8[e] = 0.f;
    int d0 = (tid & 15) * 8;
    for (int i = tid >> 4; i < N_; i += 16) {
        uint4 v = *(const uint4*)&hg[(size_t)i * D_ + d0];
        const unsigned short* pu = (const unsigned short*)&v;
#pragma unroll
        for (int e = 0; e < 8; ++e) a8[e] += bf2f(pu[e]);
    }
    __shared__ float red[16][D_];
#pragma unroll
    for (int e = 0; e < 8; ++e) red[tid >> 4][d0 + e] = a8[e];
    __syncthreads();
    __shared__ float pooled[D_];
    if (tid < D_) {
        float s = 0.f;
#pragma unroll
        for (int grp = 0; grp < 16; ++grp) s += red[grp][tid];
        pooled[tid] = s * (1.0f / (float)N_);
    }
    __syncthreads();
    if (tid < D_) {
        float accv = 0.f;
        for (int k = 0; k < D_; ++k) accv += pooled[k] * Wo[(size_t)k * D_ + tid];
        out[(size_t)g * D_ + tid] = accv;
    }
}

// ---------------------------------------------------------------------------
extern "C" void kernel_launch(void* const* d_in, const int* in_sizes, int n_in,
                              void* d_out, int out_size, void* d_ws, size_t ws_size,
                              hipStream_t stream) {
    (void)in_sizes; (void)n_in; (void)out_size; (void)ws_size;
    const float* x  = (const float*)d_in[0];
    const float* Wn = (const float*)d_in[1];
    const float* bn = (const float*)d_in[2];
    const float* Ws = (const float*)d_in[3];
    const float* Wm = (const float*)d_in[4];
    const float* bL = (const float*)d_in[5];
    const float* we = (const float*)d_in[6];
    const float* be = (const float*)d_in[7];
    const float* Wo = (const float*)d_in[8];
    float* out = (float*)d_out;

    char* w = (char*)d_ws;
    uint32_t*           adj    = (uint32_t*)w;            w += ADJ_BYTES;
    uint16_t*           ej     = (uint16_t*)w;            w += EJ_BYTES;
    float*              ed     = (float*)w;               w += ED_BYTES;
    unsigned long long* degoff = (unsigned long long*)w;  w += DO_BYTES;
    unsigned short*     hA     = (unsigned short*)w;      w += HB_BYTES;
    unsigned short*     hAT    = (unsigned short*)w;      w += HB_BYTES;
    unsigned short*     hB     = (unsigned short*)w;      w += HB_BYTES;
    unsigned short*     hBT    = (unsigned short*)w;      w += HB_BYTES;
    unsigned short*     WsT    = (unsigned short*)w;      w += WT_BYTES;
    unsigned short*     WmT    = (unsigned short*)w;      w += WT_BYTES;

    hipFuncSetAttribute((const void*)layer_kernel,
                        hipFuncAttributeMaxDynamicSharedMemorySize, 131072);

    knn_kernel<<<G_ * ROWT, 256, 0, stream>>>(x, adj);
    eprep_kernel<<<G_, 512, 0, stream>>>(x, adj, ej, ed, degoff);
    wprep_kernel<<<(2 * L_ * D_ * D_) / 256, 256, 0, stream>>>(Ws, Wm, WsT, WmT);
    enc_kernel<<<G_, 256, 0, stream>>>(x, Wn, bn, hA, hAT);

    for (int l = 0; l < L_; ++l) {
        const unsigned short* hi  = (l & 1) ? hB  : hA;
        const unsigned short* hiT = (l & 1) ? hBT : hAT;
        unsigned short* ho  = (l & 1) ? hA  : hB;
        unsigned short* hoT = (l & 1) ? hAT : hBT;
        layer_kernel<<<G_ * 4, 512, 131072, stream>>>(ej, ed, degoff, hi, hiT, ho, hoT,
                                                      WsT, WmT, bL, we, be, l);
    }

    pool_kernel<<<G_, 256, 0, stream>>>(hA, Wo, out);
}

// Round 5
// 589.479 us; speedup vs baseline: 2.1033x; 2.1033x over previous
//
#include <hip/hip_runtime.h>
#include <hip/hip_bf16.h>
#include <stdint.h>

// Problem constants (S=8, B=16, N=500, D=128, K=50, L=6)
#define G_   128
#define N_   500
#define NP_  512          // padded N (stride)
#define D_   128
#define K_   50
#define L_   6
#define NW_  16           // adjacency words per row
#define ROWT 125

typedef __attribute__((ext_vector_type(8))) short bf16x8;
typedef __attribute__((ext_vector_type(4))) float f32x4;

#define ADJ_BYTES  ((size_t)G_ * N_ * NW_ * 4)
#define ADJS_BYTES ((size_t)G_ * NP_ * NW_ * 4)
#define HB_BYTES   ((size_t)G_ * NP_ * D_ * 2)     // bf16 h or hT buffer
#define WT_BYTES   ((size_t)L_ * D_ * D_ * 2)      // bf16 transposed weights

__device__ __forceinline__ float silu_f(float z) {
    return z * __builtin_amdgcn_rcpf(1.0f + __expf(-z));
}
__device__ __forceinline__ unsigned short f2bf(float f) {
    uint32_t u = __float_as_uint(f);
    u += 0x7fffu + ((u >> 16) & 1u);
    return (unsigned short)(u >> 16);
}
__device__ __forceinline__ float bf2f(unsigned short s) {
    return __uint_as_float(((uint32_t)s) << 16);
}

// ---------------------------------------------------------------------------
// K0: kNN via exact bitwise binary-search of the 50th smallest distance.
// Distances lie in [1e-6, 2) -> float bits 30..28 fixed (0,1,1): start the
// prefix at 0x30000000, search 28 bits. Ballot-count tie fast path.
// ---------------------------------------------------------------------------
__global__ __launch_bounds__(256) void knn_kernel(const float* __restrict__ x,
                                                  uint32_t* __restrict__ adj) {
    int g    = blockIdx.x / ROWT;
    int tile = blockIdx.x % ROWT;
    int wv   = threadIdx.x >> 6;
    int lane = threadIdx.x & 63;
    int i    = tile * 4 + wv;

    __shared__ float2 c[N_];
    for (int t = threadIdx.x; t < N_; t += 256)
        c[t] = ((const float2*)x)[(size_t)g * N_ + t];
    __syncthreads();

    float2 ci = c[i];
    uint32_t kb[8];
#pragma unroll
    for (int r = 0; r < 8; ++r) {
        int j = lane + r * 64;
        float dv;
        if (j < N_ && j != i) {
            float dx = ci.x - c[j].x, dy = ci.y - c[j].y;
            dv = sqrtf(dx * dx + dy * dy + 1e-12f);
        } else {
            dv = 3.0e38f;
        }
        kb[r] = __float_as_uint(dv);
    }

    uint32_t prefix = 0x30000000u;
    for (int bit = 27; bit >= 0; --bit) {
        uint32_t cand = prefix | (1u << bit);
        int cnt = 0;
#pragma unroll
        for (int r = 0; r < 8; ++r)
            cnt += __popcll(__ballot(kb[r] < cand));
        if (cnt < K_) prefix = cand;
    }

    unsigned long long sel[8];
    int cntless = 0;
#pragma unroll
    for (int r = 0; r < 8; ++r) {
        sel[r] = __ballot(kb[r] < prefix);
        cntless += __popcll(sel[r]);
    }
    int rem = K_ - cntless;
    unsigned long long tb[8];
    int tietot = 0;
#pragma unroll
    for (int r = 0; r < 8; ++r) {
        tb[r] = __ballot(kb[r] == prefix);
        tietot += __popcll(tb[r]);
    }
    if (tietot == rem) {
#pragma unroll
        for (int r = 0; r < 8; ++r) sel[r] |= tb[r];
    } else {
#pragma unroll
        for (int r = 0; r < 8; ++r) {
            unsigned long long t2 = tb[r];
            while (rem > 0 && t2) {
                unsigned long long lb = t2 & (~t2 + 1ull);
                sel[r] |= lb;
                t2 ^= lb;
                --rem;
            }
        }
    }

    uint32_t* arow = adj + ((size_t)g * N_ + i) * NW_;
#pragma unroll
    for (int r = 0; r < 8; ++r) {
        if (lane == 2 * r)     arow[2 * r]     = (uint32_t)sel[r];
        if (lane == 2 * r + 1) arow[2 * r + 1] = (uint32_t)(sel[r] >> 32);
    }
}

// ---------------------------------------------------------------------------
// K0b: symmetrize bitmask (A |= A^T) into padded adjS (rows 500..511 = 0).
// ---------------------------------------------------------------------------
__global__ __launch_bounds__(512) void sym_kernel(const uint32_t* __restrict__ adj,
                                                  uint32_t* __restrict__ adjS) {
    int g = blockIdx.x, tid = threadIdx.x;
    __shared__ uint32_t am[N_][NW_];
    const uint32_t* ag = adj + (size_t)g * N_ * NW_;
    for (int t = tid; t < N_ * NW_; t += 512) ((uint32_t*)am)[t] = ag[t];
    __syncthreads();
    uint32_t* og = adjS + (size_t)g * NP_ * NW_;
    for (int idx = tid; idx < N_ * NW_; idx += 512) {
        int ii = idx >> 4, w = idx & 15;
        uint32_t v = am[ii][w];
        int jb = w << 5;
        int jmax = (jb + 32 <= N_) ? 32 : (N_ - jb);
        uint32_t wi = (uint32_t)ii >> 5, bi = ii & 31;
        for (int b = 0; b < jmax; ++b)
            v |= ((am[jb + b][wi] >> bi) & 1u) << b;
        og[ii * NW_ + w] = v;
    }
    for (int idx = N_ * NW_ + tid; idx < NP_ * NW_; idx += 512)
        og[idx] = 0;
}

// ---------------------------------------------------------------------------
// K0c: transpose weights to bf16: WT[l][dout][din] = bf16(W[l][din][dout])
// ---------------------------------------------------------------------------
__global__ __launch_bounds__(256) void wprep_kernel(const float* __restrict__ Ws,
                                                    const float* __restrict__ Wm,
                                                    unsigned short* __restrict__ WsT,
                                                    unsigned short* __restrict__ WmT) {
    int idx = blockIdx.x * 256 + threadIdx.x;
    int half = idx >= L_ * D_ * D_;
    int r = half ? idx - L_ * D_ * D_ : idx;
    int l = r >> 14, rr = r & 16383, dout = rr >> 7, din = rr & 127;
    const float* W = half ? Wm : Ws;
    unsigned short* O = half ? WmT : WsT;
    O[r] = f2bf(W[(size_t)l * 16384 + din * 128 + dout]);
}

// ---------------------------------------------------------------------------
// K1: h0 = silu(coords @ Wn + bn), written bf16 as h[i][d] AND hT[d][i]
// ---------------------------------------------------------------------------
__global__ __launch_bounds__(256) void enc_kernel(const float* __restrict__ x,
                                                  const float* __restrict__ Wn,
                                                  const float* __restrict__ bn,
                                                  unsigned short* __restrict__ h,
                                                  unsigned short* __restrict__ hT) {
    int g = blockIdx.x, tid = threadIdx.x;
    __shared__ float2 c[N_];
    for (int t = tid; t < N_; t += 256)
        c[t] = ((const float2*)x)[(size_t)g * N_ + t];
    __syncthreads();
    for (int o = tid; o < N_ * 16; o += 256) {
        int i = o >> 4, d0 = (o & 15) * 8;
        float2 ci = c[i];
        unsigned short u[8];
#pragma unroll
        for (int e = 0; e < 8; ++e) {
            int d = d0 + e;
            u[e] = f2bf(silu_f(ci.x * Wn[d] + ci.y * Wn[D_ + d] + bn[d]));
        }
        *(uint4*)&h[((size_t)g * NP_ + i) * D_ + d0] = *(uint4*)u;
    }
    for (int o = tid; o < D_ * 64; o += 256) {
        int d = o >> 6, io = o & 63;
        float w0 = Wn[d], w1 = Wn[D_ + d], b = bn[d];
        unsigned short u[8];
#pragma unroll
        for (int e = 0; e < 8; ++e) {
            int i = io * 8 + e;
            unsigned short val = 0;
            if (i < N_) {
                float2 ci = c[i];
                val = f2bf(silu_f(ci.x * w0 + ci.y * w1 + b));
            }
            u[e] = val;
        }
        *(uint4*)&hT[((size_t)g * D_ + d) * NP_ + io * 8] = *(uint4*)u;
    }
}

// ---------------------------------------------------------------------------
// K2: fused layer. Phase 1: mT = hT @ gateT (dense on-the-fly gate, MFMA),
// 4 j-tiles of 128 (8 barriers/block). Phase 2: h_new^T = [WsT|WmT]@[h|m]^T
// (128x128, K=256) MFMA. Epilogue: bias+silu -> LDS tiles -> coalesced uint4
// stores of hout AND houtT. Grid: G*4 with XCD-bijective swizzle.
// ---------------------------------------------------------------------------
__global__ __launch_bounds__(512, 2) void layer_kernel(
    const uint32_t* __restrict__ adjS,
    const float* __restrict__ x,
    const unsigned short* __restrict__ hin,    // [G][NP_][D_]
    const unsigned short* __restrict__ hinT,   // [G][D_][NP_]
    unsigned short* __restrict__ hout,
    unsigned short* __restrict__ houtT,
    const unsigned short* __restrict__ WsT,    // [L][dout][din] bf16
    const unsigned short* __restrict__ WmT,
    const float* __restrict__ bL,
    const float* __restrict__ we,
    const float* __restrict__ be, int l)
{
    // XCD-aware bijective swizzle (512 blocks, 8 XCDs): all 4 i-tiles of a
    // graph (and 16 graphs) land on one XCD -> hT re-reads hit that L2.
    int bid = (blockIdx.x & 7) * 64 + (blockIdx.x >> 3);
    int g  = bid >> 2;
    int it = bid & 3;
    int i0 = it * 128;
    int tid = threadIdx.x;
    int lane = tid & 63, wv = tid >> 6;
    int wrow = wv >> 2, wcol = wv & 3;   // wave tile: 64 d-rows x 32 i-cols

    extern __shared__ char lds[];
    float2*   c2    = (float2*)lds;              // [512]      4096 B
    uint32_t* am    = (uint32_t*)(lds + 4096);   // [128][16]  8192 B
    char*     hTA   = lds + 16384;               // [128 d][128 j] bf16 32 KB
    char*     gateB = lds + 49152;               // [128 i][128 j] bf16 32 KB (ends 81920)
    char*     Astk  = lds;                       // phase 2: [128 dout][256 k] 64 KB
    char*     Bstk  = lds + 65536;               // phase 2: [128 i][256 k]    64 KB
    char*     tileI = lds;                       // epilogue: [128 i][272 B]
    char*     tileT = lds + 34816;               // epilogue: [128 d][272 B]

    // stage coords + this tile's adjacency rows
    for (int t = tid; t < N_; t += 512)
        c2[t] = ((const float2*)x)[(size_t)g * N_ + t];
    const uint32_t* aS = adjS + ((size_t)g * NP_ + i0) * NW_;
    for (int t = tid; t < 128 * NW_; t += 512) am[t] = aS[t];
    __syncthreads();

    float wel = we[l], bel = be[l];
    const unsigned short* hTg = hinT + (size_t)g * D_ * NP_;

    f32x4 acc[4][2];
#pragma unroll
    for (int a_ = 0; a_ < 4; ++a_)
#pragma unroll
        for (int b_ = 0; b_ < 2; ++b_)
            acc[a_][b_] = (f32x4){0.f, 0.f, 0.f, 0.f};

    // ---- phase 1: mT += hT_tile @ gateT_tile over 4 j-tiles of 128 ----
    for (int jt = 0; jt < 4; ++jt) {
        if (jt) __syncthreads();
        int j0t = jt * 128;
        // stage hTA [128 d][128 j] (swizzled)
#pragma unroll
        for (int p = 0; p < 4; ++p) {
            int o = tid + p * 512;
            int d = o >> 4, seg = o & 15;
            uint4 v = *(const uint4*)&hTg[(size_t)d * NP_ + j0t + seg * 8];
            int byt = (d << 8) + (seg << 4); byt ^= (d & 7) << 4;
            *(uint4*)(hTA + byt) = v;
        }
        // compute gate [128 i][128 j] bf16 (swizzled)
#pragma unroll
        for (int p = 0; p < 4; ++p) {
            int o = tid + p * 512;
            int il = o >> 4, seg = o & 15;
            int jb = j0t + seg * 8;
            uint32_t wbits = am[il * NW_ + (jb >> 5)];
            uint32_t b8 = (wbits >> (jb & 31)) & 0xffu;
            float2 ci = c2[i0 + il];
            unsigned short u[8];
#pragma unroll
            for (int e = 0; e < 8; ++e) {
                float2 cj = c2[jb + e];
                float dx = ci.x - cj.x, dy = ci.y - cj.y;
                float dist = __builtin_amdgcn_sqrtf(dx * dx + dy * dy + 1e-12f);
                float z = wel * dist + bel;
                float s = z * __builtin_amdgcn_rcpf(1.0f + __expf(-z));
                u[e] = ((b8 >> e) & 1u) ? f2bf(s) : (unsigned short)0;
            }
            int byt = (il << 8) + (seg << 4); byt ^= (il & 7) << 4;
            *(uint4*)(gateB + byt) = *(uint4*)u;
        }
        __syncthreads();
        // MFMA over k = 0..128
#pragma unroll
        for (int kk = 0; kk < 128; kk += 32) {
            int kbyte = (kk + ((lane >> 4) << 3)) << 1;
            bf16x8 af[4], bfr[2];
#pragma unroll
            for (int fr = 0; fr < 4; ++fr) {
                int d = wrow * 64 + fr * 16 + (lane & 15);
                int byt = (d << 8) + kbyte; byt ^= (d & 7) << 4;
                af[fr] = *(const bf16x8*)(hTA + byt);
            }
#pragma unroll
            for (int fc = 0; fc < 2; ++fc) {
                int i = wcol * 32 + fc * 16 + (lane & 15);
                int byt = (i << 8) + kbyte; byt ^= (i & 7) << 4;
                bfr[fc] = *(const bf16x8*)(gateB + byt);
            }
#pragma unroll
            for (int fr = 0; fr < 4; ++fr)
#pragma unroll
                for (int fc = 0; fc < 2; ++fc)
                    acc[fr][fc] = __builtin_amdgcn_mfma_f32_16x16x32_bf16(
                        af[fr], bfr[fc], acc[fr][fc], 0, 0, 0);
        }
    }

    // ---- write m frags to Bstk k=128..255 (disjoint from phase-1 LDS) ----
#pragma unroll
    for (int fr = 0; fr < 4; ++fr)
#pragma unroll
        for (int fc = 0; fc < 2; ++fc) {
            int dbase = wrow * 64 + fr * 16 + ((lane >> 4) << 2);
            int ib    = wcol * 32 + fc * 16 + (lane & 15);
            f32x4 v = acc[fr][fc];
            uint32_t p0 = (uint32_t)f2bf(v[0]) | ((uint32_t)f2bf(v[1]) << 16);
            uint32_t p1 = (uint32_t)f2bf(v[2]) | ((uint32_t)f2bf(v[3]) << 16);
            int byt = (ib << 9) + ((128 + dbase) << 1); byt ^= (ib & 7) << 4;
            *(uint32_t*)(Bstk + byt)     = p0;
            *(uint32_t*)(Bstk + byt + 4) = p1;
        }
    __syncthreads();   // phase-1 LDS reads done; overwrite with Astk / Bstk-h

    // stage Astk = [WsT | WmT] [128 dout][256 k] (swizzled)
    const unsigned short* wsp = WsT + (size_t)l * D_ * D_;
    const unsigned short* wmp = WmT + (size_t)l * D_ * D_;
#pragma unroll
    for (int p = 0; p < 8; ++p) {
        int o = tid + p * 512;
        int dout = o >> 5, ko = o & 31;
        uint4 v;
        if (ko < 16) v = *(const uint4*)&wsp[dout * 128 + ko * 8];
        else         v = *(const uint4*)&wmp[dout * 128 + (ko - 16) * 8];
        int byt = (dout << 9) + (ko << 4); byt ^= (dout & 7) << 4;
        *(uint4*)(Astk + byt) = v;
    }
    // stage Bstk h-half [128 i][k<128] (zero-fill rows >= N_)
    const unsigned short* hg = hin + (size_t)g * NP_ * D_;
#pragma unroll
    for (int p = 0; p < 4; ++p) {
        int o = tid + p * 512;
        int il = o >> 4, ko = o & 15;
        int gi = i0 + il;
        uint4 v = make_uint4(0u, 0u, 0u, 0u);
        if (gi < N_) v = *(const uint4*)&hg[(size_t)gi * D_ + ko * 8];
        int byt = (il << 9) + (ko << 4); byt ^= (il & 7) << 4;
        *(uint4*)(Bstk + byt) = v;
    }
    __syncthreads();

    // ---- phase 2: h_new^T = Astk @ Bstk^T  (128x128, K=256) ----
    f32x4 acc2[4][2];
#pragma unroll
    for (int a_ = 0; a_ < 4; ++a_)
#pragma unroll
        for (int b_ = 0; b_ < 2; ++b_)
            acc2[a_][b_] = (f32x4){0.f, 0.f, 0.f, 0.f};

#pragma unroll
    for (int kk = 0; kk < 256; kk += 32) {
        int kbyte = (kk + ((lane >> 4) << 3)) << 1;
        bf16x8 af[4], bfr[2];
#pragma unroll
        for (int fr = 0; fr < 4; ++fr) {
            int d = wrow * 64 + fr * 16 + (lane & 15);
            int byt = (d << 9) + kbyte; byt ^= (d & 7) << 4;
            af[fr] = *(const bf16x8*)(Astk + byt);
        }
#pragma unroll
        for (int fc = 0; fc < 2; ++fc) {
            int i = wcol * 32 + fc * 16 + (lane & 15);
            int byt = (i << 9) + kbyte; byt ^= (i & 7) << 4;
            bfr[fc] = *(const bf16x8*)(Bstk + byt);
        }
#pragma unroll
        for (int fr = 0; fr < 4; ++fr)
#pragma unroll
            for (int fc = 0; fc < 2; ++fc)
                acc2[fr][fc] = __builtin_amdgcn_mfma_f32_16x16x32_bf16(
                    af[fr], bfr[fc], acc2[fr][fc], 0, 0, 0);
    }

    // ---- epilogue: bias + silu -> LDS tiles -> coalesced uint4 stores ----
    __syncthreads();   // all phase-2 LDS reads done before overwrite
    const float* blp = bL + (size_t)l * D_;
#pragma unroll
    for (int fr = 0; fr < 4; ++fr)
#pragma unroll
        for (int fc = 0; fc < 2; ++fc) {
            int dbase = wrow * 64 + fr * 16 + ((lane >> 4) << 2);
            int ib = wcol * 32 + fc * 16 + (lane & 15);
            int gi = i0 + ib;
            f32x4 v = acc2[fr][fc];
            float4 bias = *(const float4*)&blp[dbase];
            float o0 = silu_f(v[0] + bias.x);
            float o1 = silu_f(v[1] + bias.y);
            float o2 = silu_f(v[2] + bias.z);
            float o3 = silu_f(v[3] + bias.w);
            if (gi >= N_) { o0 = 0.f; o1 = 0.f; o2 = 0.f; o3 = 0.f; }
            unsigned short b0 = f2bf(o0), b1 = f2bf(o1);
            unsigned short b2 = f2bf(o2), b3 = f2bf(o3);
            char* pI = tileI + ib * 272 + dbase * 2;
            *(uint32_t*)pI       = (uint32_t)b0 | ((uint32_t)b1 << 16);
            *(uint32_t*)(pI + 4) = (uint32_t)b2 | ((uint32_t)b3 << 16);
            *(unsigned short*)(tileT + (dbase    ) * 272 + ib * 2) = b0;
            *(unsigned short*)(tileT + (dbase + 1) * 272 + ib * 2) = b1;
            *(unsigned short*)(tileT + (dbase + 2) * 272 + ib * 2) = b2;
            *(unsigned short*)(tileT + (dbase + 3) * 272 + ib * 2) = b3;
        }
    __syncthreads();
    unsigned short* hgO  = hout  + (size_t)g * NP_ * D_;
    unsigned short* hgOT = houtT + (size_t)g * D_ * NP_;
#pragma unroll
    for (int p = 0; p < 4; ++p) {
        int o = tid + p * 512;        // 0..2047
        int r = o >> 4, seg = o & 15;
        uint4 vI = *(const uint4*)(tileI + r * 272 + seg * 16);
        *(uint4*)&hgO[(size_t)(i0 + r) * D_ + seg * 8] = vI;
        uint4 vT = *(const uint4*)(tileT + r * 272 + seg * 16);
        *(uint4*)&hgOT[(size_t)r * NP_ + i0 + seg * 8] = vT;
    }
}

// ---------------------------------------------------------------------------
// K4: global mean pool + output projection (f32 accumulation from bf16 h)
// ---------------------------------------------------------------------------
__global__ __launch_bounds__(256) void pool_kernel(const unsigned short* __restrict__ h,
                                                   const float* __restrict__ Wo,
                                                   float* __restrict__ out) {
    int g = blockIdx.x, tid = threadIdx.x;
    const unsigned short* hg = h + (size_t)g * NP_ * D_;
    float a8[8];
#pragma unroll
    for (int e = 0; e < 8; ++e) a8[e] = 0.f;
    int d0 = (tid & 15) * 8;
    for (int i = tid >> 4; i < N_; i += 16) {
        uint4 v = *(const uint4*)&hg[(size_t)i * D_ + d0];
        const unsigned short* pu = (const unsigned short*)&v;
#pragma unroll
        for (int e = 0; e < 8; ++e) a8[e] += bf2f(pu[e]);
    }
    __shared__ float red[16][D_];
#pragma unroll
    for (int e = 0; e < 8; ++e) red[tid >> 4][d0 + e] = a8[e];
    __syncthreads();
    __shared__ float pooled[D_];
    if (tid < D_) {
        float s = 0.f;
#pragma unroll
        for (int grp = 0; grp < 16; ++grp) s += red[grp][tid];
        pooled[tid] = s * (1.0f / (float)N_);
    }
    __syncthreads();
    if (tid < D_) {
        float accv = 0.f;
        for (int k = 0; k < D_; ++k) accv += pooled[k] * Wo[(size_t)k * D_ + tid];
        out[(size_t)g * D_ + tid] = accv;
    }
}

// ---------------------------------------------------------------------------
extern "C" void kernel_launch(void* const* d_in, const int* in_sizes, int n_in,
                              void* d_out, int out_size, void* d_ws, size_t ws_size,
                              hipStream_t stream) {
    (void)in_sizes; (void)n_in; (void)out_size; (void)ws_size;
    const float* x  = (const float*)d_in[0];
    const float* Wn = (const float*)d_in[1];
    const float* bn = (const float*)d_in[2];
    const float* Ws = (const float*)d_in[3];
    const float* Wm = (const float*)d_in[4];
    const float* bL = (const float*)d_in[5];
    const float* we = (const float*)d_in[6];
    const float* be = (const float*)d_in[7];
    const float* Wo = (const float*)d_in[8];
    float* out = (float*)d_out;

    char* w = (char*)d_ws;
    uint32_t*       adj  = (uint32_t*)w;        w += ADJ_BYTES;
    uint32_t*       adjS = (uint32_t*)w;        w += ADJS_BYTES;
    unsigned short* hA   = (unsigned short*)w;  w += HB_BYTES;
    unsigned short* hAT  = (unsigned short*)w;  w += HB_BYTES;
    unsigned short* hB   = (unsigned short*)w;  w += HB_BYTES;
    unsigned short* hBT  = (unsigned short*)w;  w += HB_BYTES;
    unsigned short* WsT  = (unsigned short*)w;  w += WT_BYTES;
    unsigned short* WmT  = (unsigned short*)w;  w += WT_BYTES;

    hipFuncSetAttribute((const void*)layer_kernel,
                        hipFuncAttributeMaxDynamicSharedMemorySize, 131072);

    knn_kernel<<<G_ * ROWT, 256, 0, stream>>>(x, adj);
    sym_kernel<<<G_, 512, 0, stream>>>(adj, adjS);
    wprep_kernel<<<(2 * L_ * D_ * D_) / 256, 256, 0, stream>>>(Ws, Wm, WsT, WmT);
    enc_kernel<<<G_, 256, 0, stream>>>(x, Wn, bn, hA, hAT);

    for (int l = 0; l < L_; ++l) {
        const unsigned short* hi  = (l & 1) ? hB  : hA;
        const unsigned short* hiT = (l & 1) ? hBT : hAT;
        unsigned short* ho  = (l & 1) ? hA  : hB;
        unsigned short* hoT = (l & 1) ? hAT : hBT;
        layer_kernel<<<G_ * 4, 512, 131072, stream>>>(adjS, x, hi, hiT, ho, hoT,
                                                      WsT, WmT, bL, we, be, l);
    }

    pool_kernel<<<G_, 256, 0, stream>>>(hA, Wo, out);
}

// Round 6
// 508.634 us; speedup vs baseline: 2.4377x; 1.1589x over previous
//
#include <hip/hip_runtime.h>
#include <hip/hip_bf16.h>
#include <stdint.h>

// Problem constants (S=8, B=16, N=500, D=128, K=50, L=6)
#define G_   128
#define N_   500
#define NP_  512          // padded N (stride)
#define D_   128
#define K_   50
#define L_   6
#define NW_  16           // adjacency words per row
#define ROWT 125

typedef __attribute__((ext_vector_type(8))) short bf16x8;
typedef __attribute__((ext_vector_type(4))) float f32x4;

#define ADJ_BYTES  ((size_t)G_ * N_ * NW_ * 4)
#define ADJS_BYTES ((size_t)G_ * NP_ * NW_ * 4)
#define HB_BYTES   ((size_t)G_ * NP_ * D_ * 2)     // bf16 h or hT buffer
#define WT_BYTES   ((size_t)L_ * D_ * D_ * 2)      // bf16 transposed weights

// layer_kernel LDS layout (total 77824 B -> 2 blocks/CU)
#define L_C2 0          // float2[512]            4096 B
#define L_AM 4096       // u32 [128][16]          8192 B
#define L_B0 12288      // buf0: hTA 16K + gt 16K
#define L_B1 45056      // buf1: hTA 16K + gt 16K (ends 77824)
#define LDS_TOTAL 77824

__device__ __forceinline__ float silu_f(float z) {
    return z * __builtin_amdgcn_rcpf(1.0f + __expf(-z));
}
__device__ __forceinline__ unsigned short f2bf(float f) {
    uint32_t u = __float_as_uint(f);
    u += 0x7fffu + ((u >> 16) & 1u);
    return (unsigned short)(u >> 16);
}
__device__ __forceinline__ float bf2f(unsigned short s) {
    return __uint_as_float(((uint32_t)s) << 16);
}

// ---------------------------------------------------------------------------
// K0: kNN via exact bitwise binary-search of the 50th-smallest SQUARED
// distance (sqrt is monotonic -> same set). d^2 < 2.0 -> bit30==0, search
// bits 29..0. One wave per row, plain bitmask stores.
// ---------------------------------------------------------------------------
__global__ __launch_bounds__(256) void knn_kernel(const float* __restrict__ x,
                                                  uint32_t* __restrict__ adj) {
    int g    = blockIdx.x / ROWT;
    int tile = blockIdx.x % ROWT;
    int wv   = threadIdx.x >> 6;
    int lane = threadIdx.x & 63;
    int i    = tile * 4 + wv;

    __shared__ float2 c[N_];
    for (int t = threadIdx.x; t < N_; t += 256)
        c[t] = ((const float2*)x)[(size_t)g * N_ + t];
    __syncthreads();

    float2 ci = c[i];
    uint32_t kb[8];
#pragma unroll
    for (int r = 0; r < 8; ++r) {
        int j = lane + r * 64;
        float dv;
        if (j < N_ && j != i) {
            float dx = ci.x - c[j].x, dy = ci.y - c[j].y;
            dv = dx * dx + dy * dy;          // squared distance: same order
        } else {
            dv = 3.0e38f;
        }
        kb[r] = __float_as_uint(dv);
    }

    uint32_t prefix = 0;
    for (int bit = 29; bit >= 0; --bit) {
        uint32_t cand = prefix | (1u << bit);
        int cnt = 0;
#pragma unroll
        for (int r = 0; r < 8; ++r)
            cnt += __popcll(__ballot(kb[r] < cand));
        if (cnt < K_) prefix = cand;
    }

    unsigned long long sel[8];
    int cntless = 0;
#pragma unroll
    for (int r = 0; r < 8; ++r) {
        sel[r] = __ballot(kb[r] < prefix);
        cntless += __popcll(sel[r]);
    }
    int rem = K_ - cntless;
    unsigned long long tb[8];
    int tietot = 0;
#pragma unroll
    for (int r = 0; r < 8; ++r) {
        tb[r] = __ballot(kb[r] == prefix);
        tietot += __popcll(tb[r]);
    }
    if (tietot == rem) {
#pragma unroll
        for (int r = 0; r < 8; ++r) sel[r] |= tb[r];
    } else {
#pragma unroll
        for (int r = 0; r < 8; ++r) {
            unsigned long long t2 = tb[r];
            while (rem > 0 && t2) {
                unsigned long long lb = t2 & (~t2 + 1ull);
                sel[r] |= lb;
                t2 ^= lb;
                --rem;
            }
        }
    }

    uint32_t* arow = adj + ((size_t)g * N_ + i) * NW_;
#pragma unroll
    for (int r = 0; r < 8; ++r) {
        if (lane == 2 * r)     arow[2 * r]     = (uint32_t)sel[r];
        if (lane == 2 * r + 1) arow[2 * r + 1] = (uint32_t)(sel[r] >> 32);
    }
}

// ---------------------------------------------------------------------------
// K0b: symmetrize bitmask (A |= A^T) into padded adjS (rows 500..511 = 0).
// ---------------------------------------------------------------------------
__global__ __launch_bounds__(512) void sym_kernel(const uint32_t* __restrict__ adj,
                                                  uint32_t* __restrict__ adjS) {
    int g = blockIdx.x, tid = threadIdx.x;
    __shared__ uint32_t am[N_][NW_];
    const uint32_t* ag = adj + (size_t)g * N_ * NW_;
    for (int t = tid; t < N_ * NW_; t += 512) ((uint32_t*)am)[t] = ag[t];
    __syncthreads();
    uint32_t* og = adjS + (size_t)g * NP_ * NW_;
    for (int idx = tid; idx < N_ * NW_; idx += 512) {
        int ii = idx >> 4, w = idx & 15;
        uint32_t v = am[ii][w];
        int jb = w << 5;
        int jmax = (jb + 32 <= N_) ? 32 : (N_ - jb);
        uint32_t wi = (uint32_t)ii >> 5, bi = ii & 31;
        for (int b = 0; b < jmax; ++b)
            v |= ((am[jb + b][wi] >> bi) & 1u) << b;
        og[ii * NW_ + w] = v;
    }
    for (int idx = N_ * NW_ + tid; idx < NP_ * NW_; idx += 512)
        og[idx] = 0;
}

// ---------------------------------------------------------------------------
// K0c: transpose weights to bf16: WT[l][dout][din] = bf16(W[l][din][dout])
// ---------------------------------------------------------------------------
__global__ __launch_bounds__(256) void wprep_kernel(const float* __restrict__ Ws,
                                                    const float* __restrict__ Wm,
                                                    unsigned short* __restrict__ WsT,
                                                    unsigned short* __restrict__ WmT) {
    int idx = blockIdx.x * 256 + threadIdx.x;
    int half = idx >= L_ * D_ * D_;
    int r = half ? idx - L_ * D_ * D_ : idx;
    int l = r >> 14, rr = r & 16383, dout = rr >> 7, din = rr & 127;
    const float* W = half ? Wm : Ws;
    unsigned short* O = half ? WmT : WsT;
    O[r] = f2bf(W[(size_t)l * 16384 + din * 128 + dout]);
}

// ---------------------------------------------------------------------------
// K1: h0 = silu(coords @ Wn + bn), written bf16 as h[i][d] AND hT[d][i]
// ---------------------------------------------------------------------------
__global__ __launch_bounds__(256) void enc_kernel(const float* __restrict__ x,
                                                  const float* __restrict__ Wn,
                                                  const float* __restrict__ bn,
                                                  unsigned short* __restrict__ h,
                                                  unsigned short* __restrict__ hT) {
    int g = blockIdx.x, tid = threadIdx.x;
    __shared__ float2 c[N_];
    for (int t = tid; t < N_; t += 256)
        c[t] = ((const float2*)x)[(size_t)g * N_ + t];
    __syncthreads();
    for (int o = tid; o < N_ * 16; o += 256) {
        int i = o >> 4, d0 = (o & 15) * 8;
        float2 ci = c[i];
        unsigned short u[8];
#pragma unroll
        for (int e = 0; e < 8; ++e) {
            int d = d0 + e;
            u[e] = f2bf(silu_f(ci.x * Wn[d] + ci.y * Wn[D_ + d] + bn[d]));
        }
        *(uint4*)&h[((size_t)g * NP_ + i) * D_ + d0] = *(uint4*)u;
    }
    for (int o = tid; o < D_ * 64; o += 256) {
        int d = o >> 6, io = o & 63;
        float w0 = Wn[d], w1 = Wn[D_ + d], b = bn[d];
        unsigned short u[8];
#pragma unroll
        for (int e = 0; e < 8; ++e) {
            int i = io * 8 + e;
            unsigned short val = 0;
            if (i < N_) {
                float2 ci = c[i];
                val = f2bf(silu_f(ci.x * w0 + ci.y * w1 + b));
            }
            u[e] = val;
        }
        *(uint4*)&hT[((size_t)g * D_ + d) * NP_ + io * 8] = *(uint4*)u;
    }
}

// ---------------------------------------------------------------------------
// K2: fused layer, 76 KB LDS -> 2 blocks/CU.
// Phase 1: mT = hT @ gateT, 8 j-tiles of 64, DOUBLE-BUFFERED (stage+gate next
// while MFMA current; 1 barrier/tile). Phase 2: acc2 = WmT@m^T then += WsT@h^T
// (two K=128 passes reusing the two 32 KB buffers). Epilogue via LDS tiles ->
// coalesced uint4 stores of hout and houtT. Grid G*4, XCD-bijective swizzle.
// ---------------------------------------------------------------------------
__global__ __launch_bounds__(512, 4) void layer_kernel(
    const uint32_t* __restrict__ adjS,
    const float* __restrict__ x,
    const unsigned short* __restrict__ hin,    // [G][NP_][D_]
    const unsigned short* __restrict__ hinT,   // [G][D_][NP_]
    unsigned short* __restrict__ hout,
    unsigned short* __restrict__ houtT,
    const unsigned short* __restrict__ WsT,    // [L][dout][din] bf16
    const unsigned short* __restrict__ WmT,
    const float* __restrict__ bL,
    const float* __restrict__ we,
    const float* __restrict__ be, int l)
{
    int bid = (blockIdx.x & 7) * 64 + (blockIdx.x >> 3);   // XCD-bijective
    int g  = bid >> 2;
    int it = bid & 3;
    int i0 = it * 128;
    int tid = threadIdx.x;
    int lane = tid & 63, wv = tid >> 6;
    int wrow = wv >> 2, wcol = wv & 3;   // wave tile: 64 d-rows x 32 i-cols

    extern __shared__ char lds[];
    float2*   c2 = (float2*)(lds + L_C2);
    uint32_t* am = (uint32_t*)(lds + L_AM);
    char*     tileI = lds;               // epilogue [128 i][272 B]
    char*     tileT = lds + 34816;       // epilogue [128 d][272 B]

    for (int t = tid; t < N_; t += 512)
        c2[t] = ((const float2*)x)[(size_t)g * N_ + t];
    const uint32_t* aS = adjS + ((size_t)g * NP_ + i0) * NW_;
    for (int t = tid; t < 128 * NW_; t += 512) am[t] = aS[t];
    __syncthreads();

    float wel = we[l], bel = be[l];
    const unsigned short* hTg = hinT + (size_t)g * D_ * NP_;

    // stage hTA [128 d][64 j] + gate [128 i][64 j] into buffer `buf`
    auto stage = [&](char* buf, int jt) {
        int j0t = jt * 64;
        char* hTA   = buf;
        char* gateB = buf + 16384;
        // hTA: 2 x uint4 per thread
        uint4 hv[2];
#pragma unroll
        for (int p = 0; p < 2; ++p) {
            int o = tid + p * 512;
            int d = o >> 3, jo = o & 7;
            hv[p] = *(const uint4*)&hTg[(size_t)d * NP_ + j0t + jo * 8];
        }
        // gate: 2 groups of 8 elems per thread
#pragma unroll
        for (int p = 0; p < 2; ++p) {
            int o = tid + p * 512;
            int il = o >> 3, jo = o & 7;
            int jb = j0t + jo * 8;
            uint32_t wbits = am[il * NW_ + (jb >> 5)];
            uint32_t b8 = (wbits >> (jb & 31)) & 0xffu;
            float2 ci = c2[i0 + il];
            unsigned short u[8];
#pragma unroll
            for (int e = 0; e < 8; ++e) {
                float2 cj = c2[jb + e];
                float dx = ci.x - cj.x, dy = ci.y - cj.y;
                float dist = __builtin_amdgcn_sqrtf(dx * dx + dy * dy + 1e-12f);
                float z = wel * dist + bel;
                float s = z * __builtin_amdgcn_rcpf(1.0f + __expf(-z));
                u[e] = ((b8 >> e) & 1u) ? f2bf(s) : (unsigned short)0;
            }
            int byt = (il << 7) + (jo << 4); byt ^= (il & 7) << 4;
            *(uint4*)(gateB + byt) = *(uint4*)u;
        }
#pragma unroll
        for (int p = 0; p < 2; ++p) {
            int o = tid + p * 512;
            int d = o >> 3, jo = o & 7;
            int byt = (d << 7) + (jo << 4); byt ^= (d & 7) << 4;
            *(uint4*)(hTA + byt) = hv[p];
        }
    };

    f32x4 acc[4][2];
#pragma unroll
    for (int a_ = 0; a_ < 4; ++a_)
#pragma unroll
        for (int b_ = 0; b_ < 2; ++b_)
            acc[a_][b_] = (f32x4){0.f, 0.f, 0.f, 0.f};

    // ---- phase 1: 8 j-tiles of 64, double-buffered ----
    stage(lds + L_B0, 0);
    __syncthreads();
    for (int jt = 0; jt < 8; ++jt) {
        char* cur = lds + ((jt & 1) ? L_B1 : L_B0);
        if (jt < 7) stage(lds + ((jt & 1) ? L_B0 : L_B1), jt + 1);
        char* hTA = cur, *gateB = cur + 16384;
#pragma unroll
        for (int kk = 0; kk < 64; kk += 32) {
            int kbyte = (kk + ((lane >> 4) << 3)) << 1;
            bf16x8 af[4], bfr[2];
#pragma unroll
            for (int fr = 0; fr < 4; ++fr) {
                int d = wrow * 64 + fr * 16 + (lane & 15);
                int byt = (d << 7) + kbyte; byt ^= (d & 7) << 4;
                af[fr] = *(const bf16x8*)(hTA + byt);
            }
#pragma unroll
            for (int fc = 0; fc < 2; ++fc) {
                int i = wcol * 32 + fc * 16 + (lane & 15);
                int byt = (i << 7) + kbyte; byt ^= (i & 7) << 4;
                bfr[fc] = *(const bf16x8*)(gateB + byt);
            }
#pragma unroll
            for (int fr = 0; fr < 4; ++fr)
#pragma unroll
                for (int fc = 0; fc < 2; ++fc)
                    acc[fr][fc] = __builtin_amdgcn_mfma_f32_16x16x32_bf16(
                        af[fr], bfr[fc], acc[fr][fc], 0, 0, 0);
        }
        __syncthreads();
    }

    // ---- phase 2 pass A: acc2 = WmT @ m^T ----
    // write m frags to buf1 as B [128 i][128 k=d] (row 256 B, swizzled)
    char* Bt = lds + L_B1;
    char* At = lds + L_B0;
#pragma unroll
    for (int fr = 0; fr < 4; ++fr)
#pragma unroll
        for (int fc = 0; fc < 2; ++fc) {
            int dbase = wrow * 64 + fr * 16 + ((lane >> 4) << 2);
            int ib    = wcol * 32 + fc * 16 + (lane & 15);
            f32x4 v = acc[fr][fc];
            uint32_t p0 = (uint32_t)f2bf(v[0]) | ((uint32_t)f2bf(v[1]) << 16);
            uint32_t p1 = (uint32_t)f2bf(v[2]) | ((uint32_t)f2bf(v[3]) << 16);
            int byt = (ib << 8) + (dbase << 1); byt ^= (ib & 7) << 4;
            *(uint32_t*)(Bt + byt)     = p0;
            *(uint32_t*)(Bt + byt + 4) = p1;
        }
    // stage A = WmT [128 dout][128 k] into buf0
    const unsigned short* wmp = WmT + (size_t)l * D_ * D_;
#pragma unroll
    for (int p = 0; p < 4; ++p) {
        int o = tid + p * 512;
        int dout = o >> 4, ko = o & 15;
        uint4 v = *(const uint4*)&wmp[dout * 128 + ko * 8];
        int byt = (dout << 8) + (ko << 4); byt ^= (dout & 7) << 4;
        *(uint4*)(At + byt) = v;
    }
    __syncthreads();

    f32x4 acc2[4][2];
#pragma unroll
    for (int a_ = 0; a_ < 4; ++a_)
#pragma unroll
        for (int b_ = 0; b_ < 2; ++b_)
            acc2[a_][b_] = (f32x4){0.f, 0.f, 0.f, 0.f};

    auto gemm128 = [&]() {
#pragma unroll
        for (int kk = 0; kk < 128; kk += 32) {
            int kbyte = (kk + ((lane >> 4) << 3)) << 1;
            bf16x8 af[4], bfr[2];
#pragma unroll
            for (int fr = 0; fr < 4; ++fr) {
                int d = wrow * 64 + fr * 16 + (lane & 15);
                int byt = (d << 8) + kbyte; byt ^= (d & 7) << 4;
                af[fr] = *(const bf16x8*)(At + byt);
            }
#pragma unroll
            for (int fc = 0; fc < 2; ++fc) {
                int i = wcol * 32 + fc * 16 + (lane & 15);
                int byt = (i << 8) + kbyte; byt ^= (i & 7) << 4;
                bfr[fc] = *(const bf16x8*)(Bt + byt);
            }
#pragma unroll
            for (int fr = 0; fr < 4; ++fr)
#pragma unroll
                for (int fc = 0; fc < 2; ++fc)
                    acc2[fr][fc] = __builtin_amdgcn_mfma_f32_16x16x32_bf16(
                        af[fr], bfr[fc], acc2[fr][fc], 0, 0, 0);
        }
    };
    gemm128();
    __syncthreads();

    // ---- phase 2 pass B: acc2 += WsT @ h^T ----
    const unsigned short* hg = hin + (size_t)g * NP_ * D_;
#pragma unroll
    for (int p = 0; p < 4; ++p) {
        int o = tid + p * 512;
        int il = o >> 4, ko = o & 15;
        int gi = i0 + il;
        uint4 v = make_uint4(0u, 0u, 0u, 0u);
        if (gi < N_) v = *(const uint4*)&hg[(size_t)gi * D_ + ko * 8];
        int byt = (il << 8) + (ko << 4); byt ^= (il & 7) << 4;
        *(uint4*)(Bt + byt) = v;
    }
    const unsigned short* wsp = WsT + (size_t)l * D_ * D_;
#pragma unroll
    for (int p = 0; p < 4; ++p) {
        int o = tid + p * 512;
        int dout = o >> 4, ko = o & 15;
        uint4 v = *(const uint4*)&wsp[dout * 128 + ko * 8];
        int byt = (dout << 8) + (ko << 4); byt ^= (dout & 7) << 4;
        *(uint4*)(At + byt) = v;
    }
    __syncthreads();
    gemm128();

    // ---- epilogue: bias + silu -> LDS tiles -> coalesced uint4 stores ----
    __syncthreads();   // all phase-2 LDS reads done before overwrite
    const float* blp = bL + (size_t)l * D_;
#pragma unroll
    for (int fr = 0; fr < 4; ++fr)
#pragma unroll
        for (int fc = 0; fc < 2; ++fc) {
            int dbase = wrow * 64 + fr * 16 + ((lane >> 4) << 2);
            int ib = wcol * 32 + fc * 16 + (lane & 15);
            int gi = i0 + ib;
            f32x4 v = acc2[fr][fc];
            float4 bias = *(const float4*)&blp[dbase];
            float o0 = silu_f(v[0] + bias.x);
            float o1 = silu_f(v[1] + bias.y);
            float o2 = silu_f(v[2] + bias.z);
            float o3 = silu_f(v[3] + bias.w);
            if (gi >= N_) { o0 = 0.f; o1 = 0.f; o2 = 0.f; o3 = 0.f; }
            unsigned short b0 = f2bf(o0), b1 = f2bf(o1);
            unsigned short b2 = f2bf(o2), b3 = f2bf(o3);
            char* pI = tileI + ib * 272 + dbase * 2;
            *(uint32_t*)pI       = (uint32_t)b0 | ((uint32_t)b1 << 16);
            *(uint32_t*)(pI + 4) = (uint32_t)b2 | ((uint32_t)b3 << 16);
            *(unsigned short*)(tileT + (dbase    ) * 272 + ib * 2) = b0;
            *(unsigned short*)(tileT + (dbase + 1) * 272 + ib * 2) = b1;
            *(unsigned short*)(tileT + (dbase + 2) * 272 + ib * 2) = b2;
            *(unsigned short*)(tileT + (dbase + 3) * 272 + ib * 2) = b3;
        }
    __syncthreads();
    unsigned short* hgO  = hout  + (size_t)g * NP_ * D_;
    unsigned short* hgOT = houtT + (size_t)g * D_ * NP_;
#pragma unroll
    for (int p = 0; p < 4; ++p) {
        int o = tid + p * 512;        // 0..2047
        int r = o >> 4, seg = o & 15;
        uint4 vI = *(const uint4*)(tileI + r * 272 + seg * 16);
        *(uint4*)&hgO[(size_t)(i0 + r) * D_ + seg * 8] = vI;
        uint4 vT = *(const uint4*)(tileT + r * 272 + seg * 16);
        *(uint4*)&hgOT[(size_t)r * NP_ + i0 + seg * 8] = vT;
    }
}

// ---------------------------------------------------------------------------
// K4: global mean pool + output projection (f32 accumulation from bf16 h)
// ---------------------------------------------------------------------------
__global__ __launch_bounds__(256) void pool_kernel(const unsigned short* __restrict__ h,
                                                   const float* __restrict__ Wo,
                                                   float* __restrict__ out) {
    int g = blockIdx.x, tid = threadIdx.x;
    const unsigned short* hg = h + (size_t)g * NP_ * D_;
    float a8[8];
#pragma unroll
    for (int e = 0; e < 8; ++e) a8[e] = 0.f;
    int d0 = (tid & 15) * 8;
    for (int i = tid >> 4; i < N_; i += 16) {
        uint4 v = *(const uint4*)&hg[(size_t)i * D_ + d0];
        const unsigned short* pu = (const unsigned short*)&v;
#pragma unroll
        for (int e = 0; e < 8; ++e) a8[e] += bf2f(pu[e]);
    }
    __shared__ float red[16][D_];
#pragma unroll
    for (int e = 0; e < 8; ++e) red[tid >> 4][d0 + e] = a8[e];
    __syncthreads();
    __shared__ float pooled[D_];
    if (tid < D_) {
        float s = 0.f;
#pragma unroll
        for (int grp = 0; grp < 16; ++grp) s += red[grp][tid];
        pooled[tid] = s * (1.0f / (float)N_);
    }
    __syncthreads();
    if (tid < D_) {
        float accv = 0.f;
        for (int k = 0; k < D_; ++k) accv += pooled[k] * Wo[(size_t)k * D_ + tid];
        out[(size_t)g * D_ + tid] = accv;
    }
}

// ---------------------------------------------------------------------------
extern "C" void kernel_launch(void* const* d_in, const int* in_sizes, int n_in,
                              void* d_out, int out_size, void* d_ws, size_t ws_size,
                              hipStream_t stream) {
    (void)in_sizes; (void)n_in; (void)out_size; (void)ws_size;
    const float* x  = (const float*)d_in[0];
    const float* Wn = (const float*)d_in[1];
    const float* bn = (const float*)d_in[2];
    const float* Ws = (const float*)d_in[3];
    const float* Wm = (const float*)d_in[4];
    const float* bL = (const float*)d_in[5];
    const float* we = (const float*)d_in[6];
    const float* be = (const float*)d_in[7];
    const float* Wo = (const float*)d_in[8];
    float* out = (float*)d_out;

    char* w = (char*)d_ws;
    uint32_t*       adj  = (uint32_t*)w;        w += ADJ_BYTES;
    uint32_t*       adjS = (uint32_t*)w;        w += ADJS_BYTES;
    unsigned short* hA   = (unsigned short*)w;  w += HB_BYTES;
    unsigned short* hAT  = (unsigned short*)w;  w += HB_BYTES;
    unsigned short* hB   = (unsigned short*)w;  w += HB_BYTES;
    unsigned short* hBT  = (unsigned short*)w;  w += HB_BYTES;
    unsigned short* WsT  = (unsigned short*)w;  w += WT_BYTES;
    unsigned short* WmT  = (unsigned short*)w;  w += WT_BYTES;

    hipFuncSetAttribute((const void*)layer_kernel,
                        hipFuncAttributeMaxDynamicSharedMemorySize, LDS_TOTAL);

    knn_kernel<<<G_ * ROWT, 256, 0, stream>>>(x, adj);
    sym_kernel<<<G_, 512, 0, stream>>>(adj, adjS);
    wprep_kernel<<<(2 * L_ * D_ * D_) / 256, 256, 0, stream>>>(Ws, Wm, WsT, WmT);
    enc_kernel<<<G_, 256, 0, stream>>>(x, Wn, bn, hA, hAT);

    for (int l = 0; l < L_; ++l) {
        const unsigned short* hi  = (l & 1) ? hB  : hA;
        const unsigned short* hiT = (l & 1) ? hBT : hAT;
        unsigned short* ho  = (l & 1) ? hA  : hB;
        unsigned short* hoT = (l & 1) ? hAT : hBT;
        layer_kernel<<<G_ * 4, 512, LDS_TOTAL, stream>>>(adjS, x, hi, hiT, ho, hoT,
                                                         WsT, WmT, bL, we, be, l);
    }

    pool_kernel<<<G_, 256, 0, stream>>>(hA, Wo, out);
}

// Round 7
// 483.581 us; speedup vs baseline: 2.5639x; 1.0518x over previous
//
#include <hip/hip_runtime.h>
#include <hip/hip_bf16.h>
#include <stdint.h>

// Problem constants (S=8, B=16, N=500, D=128, K=50, L=6)
#define G_   128
#define N_   500
#define NP_  512          // padded N (stride)
#define D_   128
#define K_   50
#define L_   6
#define NW_  16           // adjacency words per row
#define ROWT 125

typedef __attribute__((ext_vector_type(8))) short bf16x8;
typedef __attribute__((ext_vector_type(4))) float f32x4;

#define ADJ_BYTES  ((size_t)G_ * N_ * NW_ * 4)      //  4,096,000
#define EBUF_BYTES ((size_t)G_ * 32 * 1024 * 4)     // 16,777,216
#define ECNT_BYTES ((size_t)G_ * 32 * 4)            //     16,384
#define HB_BYTES   ((size_t)G_ * NP_ * D_ * 2)      // 16,777,216 each
#define WT_BYTES   ((size_t)L_ * D_ * D_ * 2)       //    196,608

// layer_kernel dynamic LDS (69,664 B -> 2 blocks/CU)
#define L_B0   0          // buf0: hTA 16K + gate 16K
#define L_B1   32768      // buf1: hTA 16K + gate 16K
#define L_ECNT 69632      // u32[8] bucket counts
#define LDS_TOTAL 69664

__device__ __forceinline__ float silu_f(float z) {
    return z * __builtin_amdgcn_rcpf(1.0f + __expf(-z));
}
__device__ __forceinline__ unsigned short f2bf(float f) {
    uint32_t u = __float_as_uint(f);
    u += 0x7fffu + ((u >> 16) & 1u);
    return (unsigned short)(u >> 16);
}
__device__ __forceinline__ float bf2f(unsigned short s) {
    return __uint_as_float(((uint32_t)s) << 16);
}

// ---------------------------------------------------------------------------
// K0: kNN via RADIX-4 binary search of the 50th-smallest squared distance
// (exact: same invariant as radix-2, half the serial chain, 3-way ILP).
// d^2 < 2.0 -> bits < 0x40000000; digits at bit pairs 28..0.
// ---------------------------------------------------------------------------
__global__ __launch_bounds__(256) void knn_kernel(const float* __restrict__ x,
                                                  uint32_t* __restrict__ adj) {
    int g    = blockIdx.x / ROWT;
    int tile = blockIdx.x % ROWT;
    int wv   = threadIdx.x >> 6;
    int lane = threadIdx.x & 63;
    int i    = tile * 4 + wv;

    __shared__ float2 c[N_];
    for (int t = threadIdx.x; t < N_; t += 256)
        c[t] = ((const float2*)x)[(size_t)g * N_ + t];
    __syncthreads();

    float2 ci = c[i];
    uint32_t kb[8];
#pragma unroll
    for (int r = 0; r < 8; ++r) {
        int j = lane + r * 64;
        float dv;
        if (j < N_ && j != i) {
            float dx = ci.x - c[j].x, dy = ci.y - c[j].y;
            dv = dx * dx + dy * dy;          // squared distance: same order
        } else {
            dv = 3.0e38f;
        }
        kb[r] = __float_as_uint(dv);
    }

    uint32_t prefix = 0;
    for (int bit = 28; bit >= 0; bit -= 2) {
        uint32_t c1 = prefix + (1u << bit);
        uint32_t c2 = prefix + (2u << bit);
        uint32_t c3 = prefix + (3u << bit);
        int n1 = 0, n2 = 0, n3 = 0;
#pragma unroll
        for (int r = 0; r < 8; ++r) {
            n1 += __popcll(__ballot(kb[r] < c1));
            n2 += __popcll(__ballot(kb[r] < c2));
            n3 += __popcll(__ballot(kb[r] < c3));
        }
        if (n3 < K_)      prefix = c3;
        else if (n2 < K_) prefix = c2;
        else if (n1 < K_) prefix = c1;
    }

    unsigned long long sel[8];
    int cntless = 0;
#pragma unroll
    for (int r = 0; r < 8; ++r) {
        sel[r] = __ballot(kb[r] < prefix);
        cntless += __popcll(sel[r]);
    }
    int rem = K_ - cntless;
    unsigned long long tb[8];
    int tietot = 0;
#pragma unroll
    for (int r = 0; r < 8; ++r) {
        tb[r] = __ballot(kb[r] == prefix);
        tietot += __popcll(tb[r]);
    }
    if (tietot == rem) {
#pragma unroll
        for (int r = 0; r < 8; ++r) sel[r] |= tb[r];
    } else {
#pragma unroll
        for (int r = 0; r < 8; ++r) {
            unsigned long long t2 = tb[r];
            while (rem > 0 && t2) {
                unsigned long long lb = t2 & (~t2 + 1ull);
                sel[r] |= lb;
                t2 ^= lb;
                --rem;
            }
        }
    }

    uint32_t* arow = adj + ((size_t)g * N_ + i) * NW_;
#pragma unroll
    for (int r = 0; r < 8; ++r) {
        if (lane == 2 * r)     arow[2 * r]     = (uint32_t)sel[r];
        if (lane == 2 * r + 1) arow[2 * r + 1] = (uint32_t)(sel[r] >> 32);
    }
}

// ---------------------------------------------------------------------------
// K0b: symmetrize bitmask in LDS and emit tile-bucketed edge lists:
// bucket (it,jt) holds packed u32 records (il:7 | jl:6 | distbits>>11 :19)
// for edges i in [it*128,it*128+128), j in [jt*64,jt*64+64).
// LDS-atomic slot counters -> fully parallel emission. One block per graph.
// ---------------------------------------------------------------------------
__global__ __launch_bounds__(512) void ebuild_kernel(const float* __restrict__ x,
                                                     const uint32_t* __restrict__ adj,
                                                     uint32_t* __restrict__ ebuf,
                                                     uint32_t* __restrict__ ecnt) {
    int g = blockIdx.x, tid = threadIdx.x;
    __shared__ uint32_t am[N_][NW_];   // 32,000 B (directed adjacency)
    __shared__ float2   c[N_];         //  4,000 B
    __shared__ uint32_t bcnt[32];

    for (int t = tid; t < N_; t += 512)
        c[t] = ((const float2*)x)[(size_t)g * N_ + t];
    const uint32_t* ag = adj + (size_t)g * N_ * NW_;
    for (int t = tid; t < N_ * NW_; t += 512)
        ((uint32_t*)am)[t] = ag[t];
    if (tid < 32) bcnt[tid] = 0;
    __syncthreads();

    // symmetrized rows for this thread's (ii,w) slots, kept in registers
    uint32_t buf[16];
    int cnt = 0;
    for (int idx = tid; idx < N_ * NW_; idx += 512) {
        int ii = idx >> 4, w = idx & 15;
        uint32_t v = am[ii][w];
        int jb = w << 5;
        int jmax = (jb + 32 <= N_) ? 32 : (N_ - jb);
        uint32_t wi = (uint32_t)ii >> 5, bi = ii & 31;
        for (int b = 0; b < jmax; ++b)
            v |= ((am[jb + b][wi] >> bi) & 1u) << b;
        buf[cnt++] = v;
    }
    __syncthreads();

    uint32_t* eg = ebuf + ((size_t)g << 15);   // g * 32 * 1024
    cnt = 0;
    for (int idx = tid; idx < N_ * NW_; idx += 512) {
        int ii = idx >> 4, w = idx & 15;
        uint32_t v = buf[cnt++];
        if (!v) continue;
        float2 ci = c[ii];
        int il = ii & 127;
        int bb = (ii >> 7) << 3;
        while (v) {
            int b = __ffs(v) - 1;
            v &= v - 1;
            int j = (w << 5) + b;
            int bucket = bb + (j >> 6);
            uint32_t slot = atomicAdd(&bcnt[bucket], 1u);
            float dx = ci.x - c[j].x, dy = ci.y - c[j].y;
            float dd = sqrtf(dx * dx + dy * dy + 1e-12f);
            uint32_t rec = ((uint32_t)il << 25) | ((uint32_t)(j & 63) << 19)
                         | (__float_as_uint(dd) >> 11);
            if (slot < 1024u)
                eg[(bucket << 10) + slot] = rec;
        }
    }
    __syncthreads();
    if (tid < 32) ecnt[(g << 5) + tid] = bcnt[tid] > 1024u ? 1024u : bcnt[tid];
}

// ---------------------------------------------------------------------------
// K0c: transpose weights to bf16: WT[l][dout][din] = bf16(W[l][din][dout])
// ---------------------------------------------------------------------------
__global__ __launch_bounds__(256) void wprep_kernel(const float* __restrict__ Ws,
                                                    const float* __restrict__ Wm,
                                                    unsigned short* __restrict__ WsT,
                                                    unsigned short* __restrict__ WmT) {
    int idx = blockIdx.x * 256 + threadIdx.x;
    int half = idx >= L_ * D_ * D_;
    int r = half ? idx - L_ * D_ * D_ : idx;
    int l = r >> 14, rr = r & 16383, dout = rr >> 7, din = rr & 127;
    const float* W = half ? Wm : Ws;
    unsigned short* O = half ? WmT : WsT;
    O[r] = f2bf(W[(size_t)l * 16384 + din * 128 + dout]);
}

// ---------------------------------------------------------------------------
// K1: h0 = silu(coords @ Wn + bn), written bf16 as h[i][d] AND hT[d][i]
// ---------------------------------------------------------------------------
__global__ __launch_bounds__(256) void enc_kernel(const float* __restrict__ x,
                                                  const float* __restrict__ Wn,
                                                  const float* __restrict__ bn,
                                                  unsigned short* __restrict__ h,
                                                  unsigned short* __restrict__ hT) {
    int g = blockIdx.x, tid = threadIdx.x;
    __shared__ float2 c[N_];
    for (int t = tid; t < N_; t += 256)
        c[t] = ((const float2*)x)[(size_t)g * N_ + t];
    __syncthreads();
    for (int o = tid; o < N_ * 16; o += 256) {
        int i = o >> 4, d0 = (o & 15) * 8;
        float2 ci = c[i];
        unsigned short u[8];
#pragma unroll
        for (int e = 0; e < 8; ++e) {
            int d = d0 + e;
            u[e] = f2bf(silu_f(ci.x * Wn[d] + ci.y * Wn[D_ + d] + bn[d]));
        }
        *(uint4*)&h[((size_t)g * NP_ + i) * D_ + d0] = *(uint4*)u;
    }
    for (int o = tid; o < D_ * 64; o += 256) {
        int d = o >> 6, io = o & 63;
        float w0 = Wn[d], w1 = Wn[D_ + d], b = bn[d];
        unsigned short u[8];
#pragma unroll
        for (int e = 0; e < 8; ++e) {
            int i = io * 8 + e;
            unsigned short val = 0;
            if (i < N_) {
                float2 ci = c[i];
                val = f2bf(silu_f(ci.x * w0 + ci.y * w1 + b));
            }
            u[e] = val;
        }
        *(uint4*)&hT[((size_t)g * D_ + d) * NP_ + io * 8] = *(uint4*)u;
    }
}

// ---------------------------------------------------------------------------
// K2: fused layer, sparse-scatter gate build.
// Phase 1: mT = hT @ gateT, 8 j-tiles of 64, double-buffered; per tile:
// zero-filled gate tile + coalesced bucket read + silu + u16 LDS scatter
// (~620 edges/tile vs 8192 dense silus). Phase 2: acc2 = WmT@m^T + WsT@h^T
// (two K=128 passes). Epilogue via LDS tiles -> coalesced uint4 stores.
// Grid G*4, XCD-bijective swizzle. 69.7 KB LDS -> 2 blocks/CU.
// ---------------------------------------------------------------------------
__global__ __launch_bounds__(512, 4) void layer_kernel(
    const uint32_t* __restrict__ ebuf,
    const uint32_t* __restrict__ ecnt,
    const unsigned short* __restrict__ hin,    // [G][NP_][D_]
    const unsigned short* __restrict__ hinT,   // [G][D_][NP_]
    unsigned short* __restrict__ hout,
    unsigned short* __restrict__ houtT,
    const unsigned short* __restrict__ WsT,    // [L][dout][din] bf16
    const unsigned short* __restrict__ WmT,
    const float* __restrict__ bL,
    const float* __restrict__ we,
    const float* __restrict__ be, int l)
{
    int bid = (blockIdx.x & 7) * 64 + (blockIdx.x >> 3);   // XCD-bijective
    int g  = bid >> 2;
    int it = bid & 3;
    int i0 = it * 128;
    int tid = threadIdx.x;
    int lane = tid & 63, wv = tid >> 6;
    int wrow = wv >> 2, wcol = wv & 3;   // wave tile: 64 d-rows x 32 i-cols

    extern __shared__ char lds[];
    uint32_t* ecnt_s = (uint32_t*)(lds + L_ECNT);
    char* tileI = lds;                   // epilogue [128 i][272 B]
    char* tileT = lds + 34816;           // epilogue [128 d][272 B]

    if (tid < 8) ecnt_s[tid] = ecnt[(g << 5) + (it << 3) + tid];

    float wel = we[l], bel = be[l];
    const unsigned short* hTg = hinT + (size_t)g * D_ * NP_;
    const uint32_t* ebg = ebuf + ((size_t)g << 15) + ((size_t)it << 13);

    auto zerogate = [&](char* buf) {
        char* gb = buf + 16384;
        const uint4 z4 = make_uint4(0u, 0u, 0u, 0u);
#pragma unroll
        for (int p = 0; p < 2; ++p)
            *(uint4*)(gb + (tid + p * 512) * 16) = z4;
    };
    auto stage = [&](char* buf, int jt) {
        char* hTA   = buf;
        char* gateB = buf + 16384;
        int j0t = jt * 64;
        uint4 hv[2];
#pragma unroll
        for (int p = 0; p < 2; ++p) {
            int o = tid + p * 512;
            int d = o >> 3, jo = o & 7;
            hv[p] = *(const uint4*)&hTg[(size_t)d * NP_ + j0t + jo * 8];
        }
        int n = (int)ecnt_s[jt];
        const uint32_t* eb = ebg + (jt << 10);
        for (int e = tid; e < n; e += 512) {
            uint32_t rec = eb[e];
            int il = rec >> 25;
            int jl = (rec >> 19) & 63;
            float dist = __uint_as_float((rec & 0x7FFFFu) << 11);
            float z = wel * dist + bel;
            float s = z * __builtin_amdgcn_rcpf(1.0f + __expf(-z));
            int byt = (il << 7) + (jl << 1);
            byt ^= (il & 7) << 4;
            *(unsigned short*)(gateB + byt) = f2bf(s);
        }
#pragma unroll
        for (int p = 0; p < 2; ++p) {
            int o = tid + p * 512;
            int d = o >> 3, jo = o & 7;
            int byt = (d << 7) + (jo << 4); byt ^= (d & 7) << 4;
            *(uint4*)(hTA + byt) = hv[p];
        }
    };

    f32x4 acc[4][2];
#pragma unroll
    for (int a_ = 0; a_ < 4; ++a_)
#pragma unroll
        for (int b_ = 0; b_ < 2; ++b_)
            acc[a_][b_] = (f32x4){0.f, 0.f, 0.f, 0.f};

    // ---- phase 1: 8 j-tiles of 64, double-buffered sparse gate ----
    zerogate(lds + L_B0);
    zerogate(lds + L_B1);
    __syncthreads();              // zeros + ecnt_s visible
    stage(lds + L_B0, 0);
    __syncthreads();

    for (int jt = 0; jt < 8; ++jt) {
        char* cur = lds + ((jt & 1) ? L_B1 : L_B0);
        if (jt < 7) stage(lds + ((jt & 1) ? L_B0 : L_B1), jt + 1);
        char* hTA = cur, *gateB = cur + 16384;
#pragma unroll
        for (int kk = 0; kk < 64; kk += 32) {
            int kbyte = (kk + ((lane >> 4) << 3)) << 1;
            bf16x8 af[4], bfr[2];
#pragma unroll
            for (int fr = 0; fr < 4; ++fr) {
                int d = wrow * 64 + fr * 16 + (lane & 15);
                int byt = (d << 7) + kbyte; byt ^= (d & 7) << 4;
                af[fr] = *(const bf16x8*)(hTA + byt);
            }
#pragma unroll
            for (int fc = 0; fc < 2; ++fc) {
                int i = wcol * 32 + fc * 16 + (lane & 15);
                int byt = (i << 7) + kbyte; byt ^= (i & 7) << 4;
                bfr[fc] = *(const bf16x8*)(gateB + byt);
            }
#pragma unroll
            for (int fr = 0; fr < 4; ++fr)
#pragma unroll
                for (int fc = 0; fc < 2; ++fc)
                    acc[fr][fc] = __builtin_amdgcn_mfma_f32_16x16x32_bf16(
                        af[fr], bfr[fc], acc[fr][fc], 0, 0, 0);
        }
        __syncthreads();          // stage writes visible; cur reads done
        if (jt < 6) zerogate(cur);
        __syncthreads();          // zero visible before next scatter into cur
    }

    // ---- phase 2 pass A: acc2 = WmT @ m^T ----
    char* Bt = lds + L_B1;
    char* At = lds + L_B0;
#pragma unroll
    for (int fr = 0; fr < 4; ++fr)
#pragma unroll
        for (int fc = 0; fc < 2; ++fc) {
            int dbase = wrow * 64 + fr * 16 + ((lane >> 4) << 2);
            int ib    = wcol * 32 + fc * 16 + (lane & 15);
            f32x4 v = acc[fr][fc];
            uint32_t p0 = (uint32_t)f2bf(v[0]) | ((uint32_t)f2bf(v[1]) << 16);
            uint32_t p1 = (uint32_t)f2bf(v[2]) | ((uint32_t)f2bf(v[3]) << 16);
            int byt = (ib << 8) + (dbase << 1); byt ^= (ib & 7) << 4;
            *(uint32_t*)(Bt + byt)     = p0;
            *(uint32_t*)(Bt + byt + 4) = p1;
        }
    const unsigned short* wmp = WmT + (size_t)l * D_ * D_;
#pragma unroll
    for (int p = 0; p < 4; ++p) {
        int o = tid + p * 512;
        int dout = o >> 4, ko = o & 15;
        uint4 v = *(const uint4*)&wmp[dout * 128 + ko * 8];
        int byt = (dout << 8) + (ko << 4); byt ^= (dout & 7) << 4;
        *(uint4*)(At + byt) = v;
    }
    __syncthreads();

    f32x4 acc2[4][2];
#pragma unroll
    for (int a_ = 0; a_ < 4; ++a_)
#pragma unroll
        for (int b_ = 0; b_ < 2; ++b_)
            acc2[a_][b_] = (f32x4){0.f, 0.f, 0.f, 0.f};

    auto gemm128 = [&]() {
#pragma unroll
        for (int kk = 0; kk < 128; kk += 32) {
            int kbyte = (kk + ((lane >> 4) << 3)) << 1;
            bf16x8 af[4], bfr[2];
#pragma unroll
            for (int fr = 0; fr < 4; ++fr) {
                int d = wrow * 64 + fr * 16 + (lane & 15);
                int byt = (d << 8) + kbyte; byt ^= (d & 7) << 4;
                af[fr] = *(const bf16x8*)(At + byt);
            }
#pragma unroll
            for (int fc = 0; fc < 2; ++fc) {
                int i = wcol * 32 + fc * 16 + (lane & 15);
                int byt = (i << 8) + kbyte; byt ^= (i & 7) << 4;
                bfr[fc] = *(const bf16x8*)(Bt + byt);
            }
#pragma unroll
            for (int fr = 0; fr < 4; ++fr)
#pragma unroll
                for (int fc = 0; fc < 2; ++fc)
                    acc2[fr][fc] = __builtin_amdgcn_mfma_f32_16x16x32_bf16(
                        af[fr], bfr[fc], acc2[fr][fc], 0, 0, 0);
        }
    };
    gemm128();
    __syncthreads();

    // ---- phase 2 pass B: acc2 += WsT @ h^T ----
    const unsigned short* hg = hin + (size_t)g * NP_ * D_;
#pragma unroll
    for (int p = 0; p < 4; ++p) {
        int o = tid + p * 512;
        int il = o >> 4, ko = o & 15;
        int gi = i0 + il;
        uint4 v = make_uint4(0u, 0u, 0u, 0u);
        if (gi < N_) v = *(const uint4*)&hg[(size_t)gi * D_ + ko * 8];
        int byt = (il << 8) + (ko << 4); byt ^= (il & 7) << 4;
        *(uint4*)(Bt + byt) = v;
    }
    const unsigned short* wsp = WsT + (size_t)l * D_ * D_;
#pragma unroll
    for (int p = 0; p < 4; ++p) {
        int o = tid + p * 512;
        int dout = o >> 4, ko = o & 15;
        uint4 v = *(const uint4*)&wsp[dout * 128 + ko * 8];
        int byt = (dout << 8) + (ko << 4); byt ^= (dout & 7) << 4;
        *(uint4*)(At + byt) = v;
    }
    __syncthreads();
    gemm128();

    // ---- epilogue: bias + silu -> LDS tiles -> coalesced uint4 stores ----
    __syncthreads();   // all phase-2 LDS reads done before overwrite
    const float* blp = bL + (size_t)l * D_;
#pragma unroll
    for (int fr = 0; fr < 4; ++fr)
#pragma unroll
        for (int fc = 0; fc < 2; ++fc) {
            int dbase = wrow * 64 + fr * 16 + ((lane >> 4) << 2);
            int ib = wcol * 32 + fc * 16 + (lane & 15);
            int gi = i0 + ib;
            f32x4 v = acc2[fr][fc];
            float4 bias = *(const float4*)&blp[dbase];
            float o0 = silu_f(v[0] + bias.x);
            float o1 = silu_f(v[1] + bias.y);
            float o2 = silu_f(v[2] + bias.z);
            float o3 = silu_f(v[3] + bias.w);
            if (gi >= N_) { o0 = 0.f; o1 = 0.f; o2 = 0.f; o3 = 0.f; }
            unsigned short b0 = f2bf(o0), b1 = f2bf(o1);
            unsigned short b2 = f2bf(o2), b3 = f2bf(o3);
            char* pI = tileI + ib * 272 + dbase * 2;
            *(uint32_t*)pI       = (uint32_t)b0 | ((uint32_t)b1 << 16);
            *(uint32_t*)(pI + 4) = (uint32_t)b2 | ((uint32_t)b3 << 16);
            *(unsigned short*)(tileT + (dbase    ) * 272 + ib * 2) = b0;
            *(unsigned short*)(tileT + (dbase + 1) * 272 + ib * 2) = b1;
            *(unsigned short*)(tileT + (dbase + 2) * 272 + ib * 2) = b2;
            *(unsigned short*)(tileT + (dbase + 3) * 272 + ib * 2) = b3;
        }
    __syncthreads();
    unsigned short* hgO  = hout  + (size_t)g * NP_ * D_;
    unsigned short* hgOT = houtT + (size_t)g * D_ * NP_;
#pragma unroll
    for (int p = 0; p < 4; ++p) {
        int o = tid + p * 512;        // 0..2047
        int r = o >> 4, seg = o & 15;
        uint4 vI = *(const uint4*)(tileI + r * 272 + seg * 16);
        *(uint4*)&hgO[(size_t)(i0 + r) * D_ + seg * 8] = vI;
        uint4 vT = *(const uint4*)(tileT + r * 272 + seg * 16);
        *(uint4*)&hgOT[(size_t)r * NP_ + i0 + seg * 8] = vT;
    }
}

// ---------------------------------------------------------------------------
// K4: global mean pool + output projection (f32 accumulation from bf16 h)
// ---------------------------------------------------------------------------
__global__ __launch_bounds__(256) void pool_kernel(const unsigned short* __restrict__ h,
                                                   const float* __restrict__ Wo,
                                                   float* __restrict__ out) {
    int g = blockIdx.x, tid = threadIdx.x;
    const unsigned short* hg = h + (size_t)g * NP_ * D_;
    float a8[8];
#pragma unroll
    for (int e = 0; e < 8; ++e) a8[e] = 0.f;
    int d0 = (tid & 15) * 8;
    for (int i = tid >> 4; i < N_; i += 16) {
        uint4 v = *(const uint4*)&hg[(size_t)i * D_ + d0];
        const unsigned short* pu = (const unsigned short*)&v;
#pragma unroll
        for (int e = 0; e < 8; ++e) a8[e] += bf2f(pu[e]);
    }
    __shared__ float red[16][D_];
#pragma unroll
    for (int e = 0; e < 8; ++e) red[tid >> 4][d0 + e] = a8[e];
    __syncthreads();
    __shared__ float pooled[D_];
    if (tid < D_) {
        float s = 0.f;
#pragma unroll
        for (int grp = 0; grp < 16; ++grp) s += red[grp][tid];
        pooled[tid] = s * (1.0f / (float)N_);
    }
    __syncthreads();
    if (tid < D_) {
        float accv = 0.f;
        for (int k = 0; k < D_; ++k) accv += pooled[k] * Wo[(size_t)k * D_ + tid];
        out[(size_t)g * D_ + tid] = accv;
    }
}

// ---------------------------------------------------------------------------
extern "C" void kernel_launch(void* const* d_in, const int* in_sizes, int n_in,
                              void* d_out, int out_size, void* d_ws, size_t ws_size,
                              hipStream_t stream) {
    (void)in_sizes; (void)n_in; (void)out_size; (void)ws_size;
    const float* x  = (const float*)d_in[0];
    const float* Wn = (const float*)d_in[1];
    const float* bn = (const float*)d_in[2];
    const float* Ws = (const float*)d_in[3];
    const float* Wm = (const float*)d_in[4];
    const float* bL = (const float*)d_in[5];
    const float* we = (const float*)d_in[6];
    const float* be = (const float*)d_in[7];
    const float* Wo = (const float*)d_in[8];
    float* out = (float*)d_out;

    char* w = (char*)d_ws;
    uint32_t*       adj  = (uint32_t*)w;        w += ADJ_BYTES;
    uint32_t*       ebuf = (uint32_t*)w;        w += EBUF_BYTES;
    uint32_t*       ecnt = (uint32_t*)w;        w += ECNT_BYTES;
    unsigned short* hA   = (unsigned short*)w;  w += HB_BYTES;
    unsigned short* hAT  = (unsigned short*)w;  w += HB_BYTES;
    unsigned short* hB   = (unsigned short*)w;  w += HB_BYTES;
    unsigned short* hBT  = (unsigned short*)w;  w += HB_BYTES;
    unsigned short* WsT  = (unsigned short*)w;  w += WT_BYTES;
    unsigned short* WmT  = (unsigned short*)w;  w += WT_BYTES;

    hipFuncSetAttribute((const void*)layer_kernel,
                        hipFuncAttributeMaxDynamicSharedMemorySize, LDS_TOTAL);

    knn_kernel<<<G_ * ROWT, 256, 0, stream>>>(x, adj);
    ebuild_kernel<<<G_, 512, 0, stream>>>(x, adj, ebuf, ecnt);
    wprep_kernel<<<(2 * L_ * D_ * D_) / 256, 256, 0, stream>>>(Ws, Wm, WsT, WmT);
    enc_kernel<<<G_, 256, 0, stream>>>(x, Wn, bn, hA, hAT);

    for (int l = 0; l < L_; ++l) {
        const unsigned short* hi  = (l & 1) ? hB  : hA;
        const unsigned short* hiT = (l & 1) ? hBT : hAT;
        unsigned short* ho  = (l & 1) ? hA  : hB;
        unsigned short* hoT = (l & 1) ? hAT : hBT;
        layer_kernel<<<G_ * 4, 512, LDS_TOTAL, stream>>>(ebuf, ecnt, hi, hiT, ho, hoT,
                                                         WsT, WmT, bL, we, be, l);
    }

    pool_kernel<<<G_, 256, 0, stream>>>(hA, Wo, out);
}